// Round 9
// baseline (1171.700 us; speedup 1.0000x reference)
//
#include <hip/hip_runtime.h>
#include <hip/hip_bf16.h>

typedef __attribute__((ext_vector_type(8))) short bf16x8;
typedef __attribute__((ext_vector_type(4))) float f32x4;

#define DEV __device__ __forceinline__

static constexpr int Bn   = 64;
static constexpr int Hs   = 84;
static constexpr int HP   = 86;
static constexpr int C1c  = 128;
static constexpr int C2c  = 256;
static constexpr int NPOS = Hs * Hs;       // 7056
static constexpr float EPSf = 1e-5f;

DEV __hip_bfloat16 f2b(float v) { return __float2bfloat16(v); }

// async global(16B/lane) -> LDS (wave-uniform base + lane*16)
DEV void gload16(const void* g, void* l) {
    __builtin_amdgcn_global_load_lds(
        (const __attribute__((address_space(1))) void*)g,
        (__attribute__((address_space(3))) void*)l, 16, 0, 0);
}

// ---------------- conv1: 3->128 direct conv + BN + ReLU, f32 in -> padded NHWC bf16 (one chunk) ----------------
__global__ __launch_bounds__(128) void conv1_k(
    const float* __restrict__ x,   // chunk base: [chb,3,84,84] f32
    const float* __restrict__ w,  const float* __restrict__ cb,
    const float* __restrict__ g,  const float* __restrict__ be,
    const float* __restrict__ mm, const float* __restrict__ vv,
    __hip_bfloat16* __restrict__ h1)        // [chb,86,86,128]
{
    __shared__ float xin[3][3][HP];
    int bi = blockIdx.x;
    int b = bi / Hs, y = bi % Hs;
    int t = threadIdx.x;

    for (int idx = t; idx < 3 * 3 * HP; idx += 128) {
        int ci = idx / (3 * HP);
        int r  = idx % (3 * HP);
        int dy = r / HP;
        int xx = r % HP;
        int iy = y + dy - 1;
        int ix = xx - 1;
        float v = 0.f;
        if (iy >= 0 && iy < Hs && ix >= 0 && ix < Hs)
            v = x[((size_t)(b * 3 + ci) * Hs + iy) * Hs + ix];
        xin[ci][dy][xx] = v;
    }
    int co = t;
    float wr[3][3][3];
    for (int ci = 0; ci < 3; ci++)
        for (int dy = 0; dy < 3; dy++)
            for (int dx = 0; dx < 3; dx++)
                wr[ci][dy][dx] = w[((co * 3 + ci) * 3 + dy) * 3 + dx];
    float scale = g[co] / sqrtf(vv[co] + EPSf);
    float bias  = (cb[co] - mm[co]) * scale + be[co];
    __syncthreads();

    for (int xp = 0; xp < Hs; xp++) {
        float acc = 0.f;
        #pragma unroll
        for (int ci = 0; ci < 3; ci++)
            #pragma unroll
            for (int dy = 0; dy < 3; dy++)
                #pragma unroll
                for (int dx = 0; dx < 3; dx++)
                    acc += xin[ci][dy][xp + dx] * wr[ci][dy][dx];
        float o = acc * scale + bias;
        o = o > 0.f ? o : 0.f;
        h1[((size_t)(b * HP + y + 1) * HP + (xp + 1)) * C1c + co] = f2b(o);
    }
}

// ---------------- zero the 1px halo of a padded NHWC chunk buffer ----------------
template <int C>
__global__ void halo_zero(__hip_bfloat16* __restrict__ h)
{
    int i = blockIdx.x;
    int b = i / 340, p = i % 340;
    int y, xx;
    if (p < 86)       { y = 0;  xx = p; }
    else if (p < 172) { y = 85; xx = p - 86; }
    else if (p < 256) { xx = 0; y = p - 172 + 1; }
    else              { xx = 85; y = p - 256 + 1; }
    h[((size_t)(b * HP + y) * HP + xx) * C + threadIdx.x] = f2b(0.f);
}

// ---------------- repack conv weights OIHW f32 -> [K/32][256][32] bf16 (k = tap*CIN + ci) ----------------
template <int CIN>
__global__ void prep_w(const float* __restrict__ w, __hip_bfloat16* __restrict__ wm)
{
    int e  = blockIdx.x * 256 + threadIdx.x;   // over (9*CIN) * 256
    int k  = e >> 8;
    int co = e & 255;
    int tap = k / CIN;
    int ci  = k % CIN;
    int ty = tap / 3, tx = tap % 3;
    wm[(size_t)(k >> 5) * 8192 + co * 32 + (k & 31)] =
        f2b(w[((size_t)(co * CIN + ci) * 3 + ty) * 3 + tx]);
}

// ---------------- per-channel BN fold: sb[0:256]=scale, sb[256:512]=bias ----------------
__global__ void prep_sb(const float* __restrict__ cb, const float* __restrict__ g,
                        const float* __restrict__ be, const float* __restrict__ mm,
                        const float* __restrict__ vv, float* __restrict__ sb)
{
    int co = threadIdx.x;
    float s = g[co] / sqrtf(vv[co] + EPSf);
    sb[co] = s;
    sb[256 + co] = (cb[co] - mm[co]) * s + be[co];
}

__global__ void zero_f32(float* __restrict__ p)
{
    p[blockIdx.x * 256 + threadIdx.x] = 0.f;
}

// ---------------- pipelined implicit-GEMM conv (3x3 SAME) ----------------
// BM=128, BN=256, BK=32; 256 thr / 4 waves (2M x 2N, wave tile 64x128).
// A: direct global->register fragments (1-step prefetch, static dbl regs).
// B: LDS double-buffer, 1-ahead global_load_lds, counted vmcnt(4),
//    sched_barrier-pinned issue order, XOR-swizzled (conflict-free, R8: 0).
// kb-OUTER/tap-INNER step order (L2 locality). grid.x = chb*NPOS/128
template <int CIN, bool POOL>
__global__ __launch_bounds__(256, 2) void conv_igemm(
    const __hip_bfloat16* __restrict__ in, const __hip_bfloat16* __restrict__ wgt,
    const float* __restrict__ sb, __hip_bfloat16* __restrict__ out, float* __restrict__ pool)
{
    constexpr int KB = CIN / 32;
    constexpr int NT = 9 * KB;                 // K-steps (36 or 72), even
    __shared__ __align__(16) unsigned short Bs[2 * 256 * 32];   // 2 x 16 KB
    __shared__ float pl[512];

    int t = threadIdx.x;
    int l = t & 63, w = t >> 6;                // 4 waves
    int lidx = l & 15, lg = l >> 4;
    int wm = w >> 1, wn = w & 1;               // wave tile: rows wm*64.., cols wn*128..

    // bijective XCD-aware swizzle (m204)
    int nwg  = (int)gridDim.x;
    int orig = (int)blockIdx.x;
    int xcd = orig & 7, idx = orig >> 3;
    int q = nwg >> 3, r = nwg & 7;
    int bx = (xcd < r ? xcd * (q + 1) : r * (q + 1) + (xcd - r) * q) + idx;
    int m0 = bx * 128;

    // ---- B staging source pointers (pre-swizzled seg; unchanged from R8) ----
    int sseg = (l & 3) ^ ((l >> 3) & 3);       // involution: seg ^ (row bits 1-2)
    int srow = w * 16 + (l >> 2);
    const __hip_bfloat16* pB0 = wgt + (size_t)(srow      ) * 32 + sseg * 8;
    const __hip_bfloat16* pB1 = wgt + (size_t)(srow +  64) * 32 + sseg * 8;
    const __hip_bfloat16* pB2 = wgt + (size_t)(srow + 128) * 32 + sseg * 8;
    const __hip_bfloat16* pB3 = wgt + (size_t)(srow + 192) * 32 + sseg * 8;
    char* BsB = (char*)Bs;

    // ---- B ds_read lane address (swizzled, within one 16 KB buffer) ----
    int swz = (lidx >> 1) & 3;
    unsigned bLane = (unsigned)((wn * 128 + lidx) * 64 + ((lg ^ swz) * 16));

    // ---- A direct-load row base pointers (per m-fragment) ----
    const __hip_bfloat16* pAr[4];
    #pragma unroll
    for (int m = 0; m < 4; m++) {
        int gm = m0 + wm * 64 + m * 16 + lidx;
        int b0 = gm / NPOS; int r0 = gm - b0 * NPOS;
        int y0 = r0 / Hs;   int x0 = r0 - y0 * Hs;
        pAr[m] = in + ((size_t)(b0 * HP + y0) * HP + x0) * CIN + lg * 8;
    }

    f32x4 acc[4][8];
    #pragma unroll
    for (int i = 0; i < 4; i++)
        #pragma unroll
        for (int j = 0; j < 8; j++)
            acc[i][j] = (f32x4){0.f, 0.f, 0.f, 0.f};
    if (POOL) { pl[t] = 0.f; pl[256 + t] = 0.f; }

    // step s -> (kb = s/9 OUTER, tap = s%9 INNER)
    auto ISSUE_B = [&](int s, unsigned cB) {
        int kb = s / 9, tap = s - kb * 9;
        size_t boff = (size_t)(tap * KB + kb) * 8192;
        gload16(pB0 + boff, BsB + cB + w * 1024);
        gload16(pB1 + boff, BsB + cB + w * 1024 + 4096);
        gload16(pB2 + boff, BsB + cB + w * 1024 + 8192);
        gload16(pB3 + boff, BsB + cB + w * 1024 + 12288);
    };
    auto LOAD_A = [&](int s, bf16x8 (&aw)[4]) {
        int kb = s / 9, tap = s - kb * 9;
        int ty = tap / 3, tx = tap - ty * 3;
        int aoff = (ty * HP + tx) * CIN + kb * 32;
        #pragma unroll
        for (int m = 0; m < 4; m++)
            aw[m] = *(const bf16x8*)(pAr[m] + aoff);
    };
    auto COMP = [&](unsigned cB, const bf16x8 (&aw)[4]) {
        bf16x8 bv[8];
        #pragma unroll
        for (int n = 0; n < 8; n++)
            bv[n] = *(const bf16x8*)(BsB + cB + bLane + n * 1024);
        __builtin_amdgcn_s_setprio(1);
        #pragma unroll
        for (int m = 0; m < 4; m++)
            #pragma unroll
            for (int n = 0; n < 8; n++)
                acc[m][n] = __builtin_amdgcn_mfma_f32_16x16x32_bf16(aw[m], bv[n], acc[m][n], 0, 0, 0);
        __builtin_amdgcn_s_setprio(0);
    };

    bf16x8 aA[4], aB[4];
    // prologue: B(0) staged, A(0) in flight
    ISSUE_B(0, 0u);
    __builtin_amdgcn_sched_barrier(0);
    LOAD_A(0, aA);
    __builtin_amdgcn_sched_barrier(0);

    for (int kt = 0; kt < NT; kt += 2) {
        // ---- half-iter A: compute step kt from buf0/aA ----
        asm volatile("s_waitcnt vmcnt(4) lgkmcnt(0)" ::: "memory");
        __builtin_amdgcn_s_barrier();
        asm volatile("" ::: "memory");
        if (kt + 1 < NT) {
            ISSUE_B(kt + 1, 16384u);
            __builtin_amdgcn_sched_barrier(0);
            LOAD_A(kt + 1, aB);
            __builtin_amdgcn_sched_barrier(0);
        }
        COMP(0u, aA);
        // ---- half-iter B: compute step kt+1 from buf1/aB ----
        asm volatile("s_waitcnt vmcnt(4) lgkmcnt(0)" ::: "memory");
        __builtin_amdgcn_s_barrier();
        asm volatile("" ::: "memory");
        if (kt + 2 < NT) {
            ISSUE_B(kt + 2, 0u);
            __builtin_amdgcn_sched_barrier(0);
            LOAD_A(kt + 2, aA);
            __builtin_amdgcn_sched_barrier(0);
        }
        COMP(16384u, aB);
    }

    // ---- epilogue ----
    float sc[8], bi2[8];
    #pragma unroll
    for (int n = 0; n < 8; n++) {
        int cn = wn * 128 + n * 16 + lidx;
        sc[n]  = sb[cn];
        bi2[n] = sb[256 + cn];
    }

    if (!POOL) {
        #pragma unroll
        for (int m = 0; m < 4; m++) {
            #pragma unroll
            for (int r2 = 0; r2 < 4; r2++) {
                int row = wm * 64 + m * 16 + lg * 4 + r2;
                int gm2 = m0 + row;
                int b2  = gm2 / NPOS;
                int rm2 = gm2 - b2 * NPOS;
                int y2  = rm2 / Hs;
                int x2  = rm2 - y2 * Hs;
                size_t ob = ((size_t)(b2 * HP + y2 + 1) * HP + (x2 + 1)) * 256;
                #pragma unroll
                for (int n = 0; n < 8; n++) {
                    float v = acc[m][n][r2] * sc[n] + bi2[n];
                    v = v > 0.f ? v : 0.f;
                    out[ob + wn * 128 + n * 16 + lidx] = f2b(v);
                }
            }
        }
    } else {
        int bs_lo   = m0 / NPOS;
        int row_lim = (bs_lo + 1) * NPOS - m0;  // rows >= row_lim belong to image bs_lo+1
        #pragma unroll
        for (int n = 0; n < 8; n++) {
            float s0 = 0.f, s1 = 0.f;
            #pragma unroll
            for (int m = 0; m < 4; m++)
                #pragma unroll
                for (int r2 = 0; r2 < 4; r2++) {
                    int row = wm * 64 + m * 16 + lg * 4 + r2;
                    float v = acc[m][n][r2] * sc[n] + bi2[n];
                    v = v > 0.f ? v : 0.f;
                    if (row < row_lim) s0 += v; else s1 += v;
                }
            int cl = wn * 128 + n * 16 + lidx;   // [0,256)
            atomicAdd(&pl[cl], s0);
            if (row_lim < 128) atomicAdd(&pl[256 + cl], s1);
        }
        __syncthreads();
        atomicAdd(&pool[bs_lo * 256 + t], pl[t]);
        if (row_lim < 128) atomicAdd(&pool[(bs_lo + 1) * 256 + t], pl[256 + t]);
    }
}

// ---------------- pool finalize: mean ----------------
__global__ void pool_div(const float* __restrict__ pool, float* __restrict__ h0)
{
    int i = blockIdx.x * 256 + threadIdx.x;
    h0[i] = pool[i] * (1.0f / (float)NPOS);
}

// ---------------- GCN attention: ew = softmax(leaky(p[row]+q[col]+ab)) over 256 edges ----------------
__global__ __launch_bounds__(256) void gcn_attn(
    const float* __restrict__ h, const float* __restrict__ aw,
    const float* __restrict__ ab, const int* __restrict__ ei,
    float* __restrict__ ew)
{
    __shared__ float p[64], q[64], red[256];
    int t = threadIdx.x;
    if (t < 64) {
        float pp = 0.f, qq = 0.f;
        for (int c = 0; c < 256; c++) {
            float hv = h[t * 256 + c];
            pp += hv * aw[c];
            qq += hv * aw[256 + c];
        }
        p[t] = pp; q[t] = qq;
    }
    __syncthreads();
    int r = ei[t], c = ei[256 + t];
    float s = p[r] + q[c] + ab[0];
    s = s >= 0.f ? s : 0.01f * s;
    red[t] = s;
    __syncthreads();
    for (int st = 128; st > 0; st >>= 1) {
        if (t < st) red[t] = fmaxf(red[t], red[t + st]);
        __syncthreads();
    }
    float mx = red[0];
    __syncthreads();
    float e = expf(s - mx);
    red[t] = e;
    __syncthreads();
    for (int st = 128; st > 0; st >>= 1) {
        if (t < st) red[t] += red[t + st];
        __syncthreads();
    }
    ew[t] = e / red[0];
}

// ---------------- GCN aggregate + linear + residual (+ReLU) ----------------
__global__ __launch_bounds__(256) void gcn_agg(
    const float* __restrict__ h, const float* __restrict__ ew, const int* __restrict__ ei,
    const float* __restrict__ lw, const float* __restrict__ lb,
    float* __restrict__ ho)
{
    __shared__ float agg[256];
    __shared__ float ewl[256];
    __shared__ int rl[256], cl[256];
    int n = blockIdx.x;
    int t = threadIdx.x;
    ewl[t] = ew[t];
    rl[t] = ei[t];
    cl[t] = ei[256 + t];
    __syncthreads();
    float a = 0.f;
    for (int e = 0; e < 256; e++)
        if (rl[e] == n) a += ewl[e] * h[cl[e] * 256 + t];
    agg[t] = a;
    __syncthreads();
    float o = 0.f;
    for (int c2 = 0; c2 < 256; c2++)
        o += agg[c2] * lw[t * 256 + c2];
    o += lb[t] + h[n * 256 + t];
    o = o > 0.f ? o : 0.f;
    ho[n * 256 + t] = o;
}

// ---------------- final fc: [64,256] @ [50,256]^T + b -> f32 out ----------------
__global__ void fc_k(const float* __restrict__ h, const float* __restrict__ fw,
                     const float* __restrict__ fb, float* __restrict__ out)
{
    int n = blockIdx.x;
    int t = threadIdx.x;
    if (t < 50) {
        float o = 0.f;
        for (int c = 0; c < 256; c++)
            o += h[n * 256 + c] * fw[t * 256 + c];
        o += fb[t];
        out[n * 50 + t] = o;
    }
}

extern "C" void kernel_launch(void* const* d_in, const int* in_sizes, int n_in,
                              void* d_out, int out_size, void* d_ws, size_t ws_size,
                              hipStream_t stream)
{
    (void)in_sizes; (void)n_in; (void)out_size;

    const float* X    = (const float*)d_in[0];
    const float* c1w  = (const float*)d_in[1];
    const float* c1b  = (const float*)d_in[2];
    const float* b1g  = (const float*)d_in[3];
    const float* b1b  = (const float*)d_in[4];
    const float* b1m  = (const float*)d_in[5];
    const float* b1v  = (const float*)d_in[6];
    const float* c2w  = (const float*)d_in[7];
    const float* c2b  = (const float*)d_in[8];
    const float* b2g  = (const float*)d_in[9];
    const float* b2b  = (const float*)d_in[10];
    const float* b2m  = (const float*)d_in[11];
    const float* b2v  = (const float*)d_in[12];
    const float* c3w  = (const float*)d_in[13];
    const float* c3b  = (const float*)d_in[14];
    const float* b3g  = (const float*)d_in[15];
    const float* b3b  = (const float*)d_in[16];
    const float* b3m  = (const float*)d_in[17];
    const float* b3v  = (const float*)d_in[18];
    const float* g1lw = (const float*)d_in[19];
    const float* g1lb = (const float*)d_in[20];
    const float* g1aw = (const float*)d_in[21];
    const float* g1ab = (const float*)d_in[22];
    const float* g2lw = (const float*)d_in[23];
    const float* g2lb = (const float*)d_in[24];
    const float* g2aw = (const float*)d_in[25];
    const float* g2ab = (const float*)d_in[26];
    const float* fcw  = (const float*)d_in[27];
    const float* fcb  = (const float*)d_in[28];
    const int*   EI   = (const int*)d_in[29];

    // runtime chunk size: largest of {64,32,16,8} that fits the workspace
    size_t fixedB = 3000000;
    int chb = 8;
    if (ws_size >= (size_t)64 * 5680128 + fixedB)      chb = 64;
    else if (ws_size >= (size_t)32 * 5680128 + fixedB) chb = 32;
    else if (ws_size >= (size_t)16 * 5680128 + fixedB) chb = 16;
    int nchunks = Bn / chb;
    int mch = chb * NPOS;                  // positions per chunk (div by 128)

    char* p = (char*)d_ws;
    auto carve = [&](size_t bytes) {
        char* r = p;
        p += (bytes + 255) & ~(size_t)255;
        return r;
    };
    __hip_bfloat16* h1c = (__hip_bfloat16*)carve((size_t)chb * HP * HP * C1c * 2);
    __hip_bfloat16* h2c = (__hip_bfloat16*)carve((size_t)chb * HP * HP * C2c * 2);
    __hip_bfloat16* wm2 = (__hip_bfloat16*)carve((size_t)9 * C1c * 256 * 2);
    __hip_bfloat16* wm3 = (__hip_bfloat16*)carve((size_t)9 * C2c * 256 * 2);
    float* sb2  = (float*)carve(512 * 4);
    float* sb3  = (float*)carve(512 * 4);
    float* pool = (float*)carve(64 * 256 * 4);
    float* h0   = (float*)carve(64 * 256 * 4);
    float* hg1  = (float*)carve(64 * 256 * 4);
    float* hg2  = (float*)carve(64 * 256 * 4);
    float* ew1  = (float*)carve(256 * 4);
    float* ew2  = (float*)carve(256 * 4);

    // prep (independent of conv outputs); halos stay zero across chunks/replays
    halo_zero<C1c><<<dim3(chb * 340), dim3(C1c), 0, stream>>>(h1c);
    halo_zero<C2c><<<dim3(chb * 340), dim3(C2c), 0, stream>>>(h2c);
    prep_w<C1c><<<dim3(9 * C1c), dim3(256), 0, stream>>>(c2w, wm2);
    prep_w<C2c><<<dim3(9 * C2c), dim3(256), 0, stream>>>(c3w, wm3);
    prep_sb<<<dim3(1), dim3(256), 0, stream>>>(c2b, b2g, b2b, b2m, b2v, sb2);
    prep_sb<<<dim3(1), dim3(256), 0, stream>>>(c3b, b3g, b3b, b3m, b3v, sb3);
    zero_f32<<<dim3(64), dim3(256), 0, stream>>>(pool);

    // conv chain, chunked over batch (chb images per chunk)
    for (int ch = 0; ch < nchunks; ch++) {
        const float* xch = X + (size_t)ch * chb * 3 * NPOS;
        conv1_k<<<dim3(chb * Hs), dim3(C1c), 0, stream>>>(
            xch, c1w, c1b, b1g, b1b, b1m, b1v, h1c);
        conv_igemm<C1c, false><<<dim3(mch / 128), dim3(256), 0, stream>>>(
            h1c, wm2, sb2, h2c, nullptr);
        conv_igemm<C2c, true ><<<dim3(mch / 128), dim3(256), 0, stream>>>(
            h2c, wm3, sb3, nullptr, pool + (size_t)ch * chb * 256);
    }
    pool_div<<<dim3(64), dim3(256), 0, stream>>>(pool, h0);

    // GCN layers + fc
    gcn_attn<<<dim3(1), dim3(256), 0, stream>>>(h0, g1aw, g1ab, EI, ew1);
    gcn_agg<<<dim3(64), dim3(256), 0, stream>>>(h0, ew1, EI, g1lw, g1lb, hg1);
    gcn_attn<<<dim3(1), dim3(256), 0, stream>>>(hg1, g2aw, g2ab, EI, ew2);
    gcn_agg<<<dim3(64), dim3(256), 0, stream>>>(hg1, ew2, EI, g2lw, g2lb, hg2);
    fc_k<<<dim3(64), dim3(64), 0, stream>>>(hg2, fcw, fcb, (float*)d_out);
}

// Round 10
// 1086.859 us; speedup vs baseline: 1.0781x; 1.0781x over previous
//
#include <hip/hip_runtime.h>
#include <hip/hip_bf16.h>

typedef __attribute__((ext_vector_type(8))) short bf16x8;
typedef __attribute__((ext_vector_type(4))) float f32x4;

#define DEV __device__ __forceinline__

static constexpr int Bn   = 64;
static constexpr int Hs   = 84;
static constexpr int HP   = 86;
static constexpr int C1c  = 128;
static constexpr int C2c  = 256;
static constexpr int NPOS = Hs * Hs;       // 7056
static constexpr float EPSf = 1e-5f;

DEV __hip_bfloat16 f2b(float v) { return __float2bfloat16(v); }

// async global(16B/lane) -> LDS (wave-uniform base + lane*16)
DEV void gload16(const void* g, void* l) {
    __builtin_amdgcn_global_load_lds(
        (const __attribute__((address_space(1))) void*)g,
        (__attribute__((address_space(3))) void*)l, 16, 0, 0);
}

// ---------------- conv1: 3->128 direct conv + BN + ReLU, f32 in -> padded NHWC bf16 (one chunk) ----------------
__global__ __launch_bounds__(128) void conv1_k(
    const float* __restrict__ x,   // chunk base: [chb,3,84,84] f32
    const float* __restrict__ w,  const float* __restrict__ cb,
    const float* __restrict__ g,  const float* __restrict__ be,
    const float* __restrict__ mm, const float* __restrict__ vv,
    __hip_bfloat16* __restrict__ h1)        // [chb,86,86,128]
{
    __shared__ float xin[3][3][HP];
    int bi = blockIdx.x;
    int b = bi / Hs, y = bi % Hs;
    int t = threadIdx.x;

    for (int idx = t; idx < 3 * 3 * HP; idx += 128) {
        int ci = idx / (3 * HP);
        int r  = idx % (3 * HP);
        int dy = r / HP;
        int xx = r % HP;
        int iy = y + dy - 1;
        int ix = xx - 1;
        float v = 0.f;
        if (iy >= 0 && iy < Hs && ix >= 0 && ix < Hs)
            v = x[((size_t)(b * 3 + ci) * Hs + iy) * Hs + ix];
        xin[ci][dy][xx] = v;
    }
    int co = t;
    float wr[3][3][3];
    for (int ci = 0; ci < 3; ci++)
        for (int dy = 0; dy < 3; dy++)
            for (int dx = 0; dx < 3; dx++)
                wr[ci][dy][dx] = w[((co * 3 + ci) * 3 + dy) * 3 + dx];
    float scale = g[co] / sqrtf(vv[co] + EPSf);
    float bias  = (cb[co] - mm[co]) * scale + be[co];
    __syncthreads();

    for (int xp = 0; xp < Hs; xp++) {
        float acc = 0.f;
        #pragma unroll
        for (int ci = 0; ci < 3; ci++)
            #pragma unroll
            for (int dy = 0; dy < 3; dy++)
                #pragma unroll
                for (int dx = 0; dx < 3; dx++)
                    acc += xin[ci][dy][xp + dx] * wr[ci][dy][dx];
        float o = acc * scale + bias;
        o = o > 0.f ? o : 0.f;
        h1[((size_t)(b * HP + y + 1) * HP + (xp + 1)) * C1c + co] = f2b(o);
    }
}

// ---------------- zero the 1px halo of a padded NHWC chunk buffer ----------------
template <int C>
__global__ void halo_zero(__hip_bfloat16* __restrict__ h)
{
    int i = blockIdx.x;
    int b = i / 340, p = i % 340;
    int y, xx;
    if (p < 86)       { y = 0;  xx = p; }
    else if (p < 172) { y = 85; xx = p - 86; }
    else if (p < 256) { xx = 0; y = p - 172 + 1; }
    else              { xx = 85; y = p - 256 + 1; }
    h[((size_t)(b * HP + y) * HP + xx) * C + threadIdx.x] = f2b(0.f);
}

// ---------------- repack conv weights OIHW f32 -> [K/32][256][32] bf16 (k = tap*CIN + ci) ----------------
template <int CIN>
__global__ void prep_w(const float* __restrict__ w, __hip_bfloat16* __restrict__ wm)
{
    int e  = blockIdx.x * 256 + threadIdx.x;   // over (9*CIN) * 256
    int k  = e >> 8;
    int co = e & 255;
    int tap = k / CIN;
    int ci  = k % CIN;
    int ty = tap / 3, tx = tap % 3;
    wm[(size_t)(k >> 5) * 8192 + co * 32 + (k & 31)] =
        f2b(w[((size_t)(co * CIN + ci) * 3 + ty) * 3 + tx]);
}

// ---------------- per-channel BN fold: sb[0:256]=scale, sb[256:512]=bias ----------------
__global__ void prep_sb(const float* __restrict__ cb, const float* __restrict__ g,
                        const float* __restrict__ be, const float* __restrict__ mm,
                        const float* __restrict__ vv, float* __restrict__ sb)
{
    int co = threadIdx.x;
    float s = g[co] / sqrtf(vv[co] + EPSf);
    sb[co] = s;
    sb[256 + co] = (cb[co] - mm[co]) * s + be[co];
}

__global__ void zero_f32(float* __restrict__ p)
{
    p[blockIdx.x * 256 + threadIdx.x] = 0.f;
}

// ---------------- 8-phase pipelined implicit-GEMM conv (3x3 SAME) ----------------
// BM=128, BN=256, BK=64 (2 sub-steps of 32); 512 thr / 8 waves (2M x 4N, wave 64x64).
// Triple-buffered LDS (3 x 48 KB), prefetch depth 2 K-tiles, counted vmcnt(6)
// at K-tile head (never 0 in steady state), 2 phases per K-tile each
// {ds_read subtile | issue 3 gload_lds | barrier | lgkmcnt(0) | 16 MFMA}.
// LDS planes: A[2kh][128][32] (+0,+8192), B[2kh][256][32] (+16384,+32768); 64B rows
// -> slot-uniform ds_read_b128 (R8 measured 0 conflicts). kb-outer/tap-inner K order.
// grid.x = chb*NPOS/128, block = 512.
template <int CIN, bool POOL>
__global__ __launch_bounds__(512, 2) void conv_igemm(
    const __hip_bfloat16* __restrict__ in, const __hip_bfloat16* __restrict__ wgt,
    const float* __restrict__ sb, __hip_bfloat16* __restrict__ out, float* __restrict__ pool)
{
    constexpr int KB = CIN / 32;
    constexpr int NK = 9 * KB / 2;             // K-tiles of 64 (18 or 36)
    constexpr unsigned BUF = 49152u;           // 48 KB per buffer
    __shared__ __align__(16) char lds[3 * 49152];
    __shared__ float pl[512];

    int t = threadIdx.x;
    int l = t & 63, w = t >> 6;                // 8 waves
    int lidx = l & 15, lg = l >> 4;
    int wm = w >> 2, wn = w & 3;               // wave tile: rows wm*64.., cols wn*64..

    // bijective XCD-aware swizzle (m204)
    int nwg  = (int)gridDim.x;
    int orig = (int)blockIdx.x;
    int xcd = orig & 7, idx = orig >> 3;
    int q = nwg >> 3, r = nwg & 7;
    int bx = (xcd < r ? xcd * (q + 1) : r * (q + 1) + (xcd - r) * q) + idx;
    int m0 = bx * 128;

    // ---- staging lane sources: lane t stages row (t>>2), 16B segment (t&3) ----
    int seg  = t & 3;
    int srow = t >> 2;                         // 0..127
    const __hip_bfloat16* pA;
    {
        int gm = m0 + srow;
        int b0 = gm / NPOS; int r0 = gm - b0 * NPOS;
        int y0 = r0 / Hs;   int x0 = r0 - y0 * Hs;
        pA = in + ((size_t)(b0 * HP + y0) * HP + x0) * CIN + seg * 8;
    }
    const __hip_bfloat16* pB = wgt + (size_t)srow * 32 + seg * 8;

    // ---- frag ds_read byte offsets (within one 48 KB buffer) ----
    unsigned aRd[4][2], bRd[4][2];
    #pragma unroll
    for (int mf = 0; mf < 4; mf++)
        #pragma unroll
        for (int kh = 0; kh < 2; kh++)
            aRd[mf][kh] = (unsigned)(kh * 8192 + (wm * 64 + mf * 16 + lidx) * 64 + lg * 16);
    #pragma unroll
    for (int nf = 0; nf < 4; nf++)
        #pragma unroll
        for (int kh = 0; kh < 2; kh++)
            bRd[nf][kh] = (unsigned)(16384 + kh * 16384 + (wn * 64 + nf * 16 + lidx) * 64 + lg * 16);

    f32x4 acc[4][4];
    #pragma unroll
    for (int i = 0; i < 4; i++)
        #pragma unroll
        for (int j = 0; j < 4; j++)
            acc[i][j] = (f32x4){0.f, 0.f, 0.f, 0.f};
    if (POOL) pl[t] = 0.f;

    // sub-step s -> (kb = s/9 OUTER, tap = s%9 INNER): L2 locality (R6/R8 lesson)
    auto AOFF = [&](int s) -> size_t {
        int kb = s / 9, tap = s - kb * 9;
        int ty = tap / 3, tx = tap - ty * 3;
        return (size_t)(ty * HP + tx) * CIN + kb * 32;
    };
    auto BOFF = [&](int s) -> size_t {
        int kb = s / 9, tap = s - kb * 9;
        return (size_t)(tap * KB + kb) * 8192;
    };
    // phase-0 staging of K-tile kt2 into buffer nb: A kh0, A kh1, B kh0 lo
    auto ISSUE_P0 = [&](int kt2, unsigned nb) {
        int s0 = 2 * kt2, s1 = s0 + 1;
        gload16(pA + AOFF(s0), lds + nb +          w * 1024);
        gload16(pA + AOFF(s1), lds + nb +  8192 + w * 1024);
        gload16(pB + BOFF(s0), lds + nb + 16384 + w * 1024);
    };
    // phase-1 staging: B kh0 hi, B kh1 lo, B kh1 hi
    auto ISSUE_P1 = [&](int kt2, unsigned nb) {
        int s0 = 2 * kt2, s1 = s0 + 1;
        gload16(pB + BOFF(s0) + 4096, lds + nb + 24576 + w * 1024);
        gload16(pB + BOFF(s1),        lds + nb + 32768 + w * 1024);
        gload16(pB + BOFF(s1) + 4096, lds + nb + 40960 + w * 1024);
    };

    // prologue: stage K-tiles 0 and 1 (12 loads in flight)
    ISSUE_P0(0, 0u); ISSUE_P1(0, 0u);
    ISSUE_P0(1, BUF); ISSUE_P1(1, BUF);

    for (int kt = 0; kt < NK; ++kt) {
        unsigned cb = (unsigned)(kt % 3) * BUF;
        unsigned nb = (unsigned)((kt + 2) % 3) * BUF;
        bool more = (kt + 2) < NK;

        // ===== phase 0: A all + B nf 0,1 =====
        if (kt + 1 < NK) asm volatile("s_waitcnt vmcnt(6)" ::: "memory");
        else             asm volatile("s_waitcnt vmcnt(0)" ::: "memory");
        __builtin_amdgcn_s_barrier();   // all waves' kt loads landed

        bf16x8 av[4][2], bv0[2][2];
        #pragma unroll
        for (int mf = 0; mf < 4; mf++)
            #pragma unroll
            for (int kh = 0; kh < 2; kh++)
                av[mf][kh] = *(const bf16x8*)(lds + cb + aRd[mf][kh]);
        #pragma unroll
        for (int nf = 0; nf < 2; nf++)
            #pragma unroll
            for (int kh = 0; kh < 2; kh++)
                bv0[nf][kh] = *(const bf16x8*)(lds + cb + bRd[nf][kh]);
        if (more) ISSUE_P0(kt + 2, nb);
        __builtin_amdgcn_s_barrier();
        asm volatile("s_waitcnt lgkmcnt(0)" ::: "memory");
        __builtin_amdgcn_sched_barrier(0);
        __builtin_amdgcn_s_setprio(1);
        #pragma unroll
        for (int kh = 0; kh < 2; kh++)
            #pragma unroll
            for (int mf = 0; mf < 4; mf++)
                #pragma unroll
                for (int nf = 0; nf < 2; nf++)
                    acc[mf][nf] = __builtin_amdgcn_mfma_f32_16x16x32_bf16(
                        av[mf][kh], bv0[nf][kh], acc[mf][nf], 0, 0, 0);
        __builtin_amdgcn_s_setprio(0);

        // ===== phase 1: A held + B nf 2,3 =====
        __builtin_amdgcn_s_barrier();
        bf16x8 bv1[2][2];
        #pragma unroll
        for (int nf = 0; nf < 2; nf++)
            #pragma unroll
            for (int kh = 0; kh < 2; kh++)
                bv1[nf][kh] = *(const bf16x8*)(lds + cb + bRd[2 + nf][kh]);
        if (more) ISSUE_P1(kt + 2, nb);
        __builtin_amdgcn_s_barrier();
        asm volatile("s_waitcnt lgkmcnt(0)" ::: "memory");
        __builtin_amdgcn_sched_barrier(0);
        __builtin_amdgcn_s_setprio(1);
        #pragma unroll
        for (int kh = 0; kh < 2; kh++)
            #pragma unroll
            for (int mf = 0; mf < 4; mf++)
                #pragma unroll
                for (int nf = 0; nf < 2; nf++)
                    acc[mf][2 + nf] = __builtin_amdgcn_mfma_f32_16x16x32_bf16(
                        av[mf][kh], bv1[nf][kh], acc[mf][2 + nf], 0, 0, 0);
        __builtin_amdgcn_s_setprio(0);
    }

    // ---- epilogue ----
    float sc[4], bi2[4];
    #pragma unroll
    for (int nf = 0; nf < 4; nf++) {
        int cn = wn * 64 + nf * 16 + lidx;
        sc[nf]  = sb[cn];
        bi2[nf] = sb[256 + cn];
    }

    if (!POOL) {
        #pragma unroll
        for (int mf = 0; mf < 4; mf++) {
            #pragma unroll
            for (int r2 = 0; r2 < 4; r2++) {
                int row = wm * 64 + mf * 16 + lg * 4 + r2;
                int gm2 = m0 + row;
                int b2  = gm2 / NPOS;
                int rm2 = gm2 - b2 * NPOS;
                int y2  = rm2 / Hs;
                int x2  = rm2 - y2 * Hs;
                size_t ob = ((size_t)(b2 * HP + y2 + 1) * HP + (x2 + 1)) * 256;
                #pragma unroll
                for (int nf = 0; nf < 4; nf++) {
                    float v = acc[mf][nf][r2] * sc[nf] + bi2[nf];
                    v = v > 0.f ? v : 0.f;
                    out[ob + wn * 64 + nf * 16 + lidx] = f2b(v);
                }
            }
        }
    } else {
        int bs_lo   = m0 / NPOS;
        int row_lim = (bs_lo + 1) * NPOS - m0;  // rows >= row_lim belong to image bs_lo+1
        __builtin_amdgcn_s_barrier();            // pl[] init visible (redundant w/ loop barriers)
        #pragma unroll
        for (int nf = 0; nf < 4; nf++) {
            float s0 = 0.f, s1 = 0.f;
            #pragma unroll
            for (int mf = 0; mf < 4; mf++)
                #pragma unroll
                for (int r2 = 0; r2 < 4; r2++) {
                    int row = wm * 64 + mf * 16 + lg * 4 + r2;
                    float v = acc[mf][nf][r2] * sc[nf] + bi2[nf];
                    v = v > 0.f ? v : 0.f;
                    if (row < row_lim) s0 += v; else s1 += v;
                }
            int cl = wn * 64 + nf * 16 + lidx;   // [0,256)
            atomicAdd(&pl[cl], s0);
            if (row_lim < 128) atomicAdd(&pl[256 + cl], s1);
        }
        __syncthreads();
        if (t < 256)
            atomicAdd(&pool[bs_lo * 256 + t], pl[t]);
        else if (row_lim < 128)
            atomicAdd(&pool[(bs_lo + 1) * 256 + (t - 256)], pl[t]);
    }
}

// ---------------- pool finalize: mean ----------------
__global__ void pool_div(const float* __restrict__ pool, float* __restrict__ h0)
{
    int i = blockIdx.x * 256 + threadIdx.x;
    h0[i] = pool[i] * (1.0f / (float)NPOS);
}

// ---------------- GCN attention: ew = softmax(leaky(p[row]+q[col]+ab)) over 256 edges ----------------
__global__ __launch_bounds__(256) void gcn_attn(
    const float* __restrict__ h, const float* __restrict__ aw,
    const float* __restrict__ ab, const int* __restrict__ ei,
    float* __restrict__ ew)
{
    __shared__ float p[64], q[64], red[256];
    int t = threadIdx.x;
    if (t < 64) {
        float pp = 0.f, qq = 0.f;
        for (int c = 0; c < 256; c++) {
            float hv = h[t * 256 + c];
            pp += hv * aw[c];
            qq += hv * aw[256 + c];
        }
        p[t] = pp; q[t] = qq;
    }
    __syncthreads();
    int r = ei[t], c = ei[256 + t];
    float s = p[r] + q[c] + ab[0];
    s = s >= 0.f ? s : 0.01f * s;
    red[t] = s;
    __syncthreads();
    for (int st = 128; st > 0; st >>= 1) {
        if (t < st) red[t] = fmaxf(red[t], red[t + st]);
        __syncthreads();
    }
    float mx = red[0];
    __syncthreads();
    float e = expf(s - mx);
    red[t] = e;
    __syncthreads();
    for (int st = 128; st > 0; st >>= 1) {
        if (t < st) red[t] += red[t + st];
        __syncthreads();
    }
    ew[t] = e / red[0];
}

// ---------------- GCN aggregate + linear + residual (+ReLU) ----------------
__global__ __launch_bounds__(256) void gcn_agg(
    const float* __restrict__ h, const float* __restrict__ ew, const int* __restrict__ ei,
    const float* __restrict__ lw, const float* __restrict__ lb,
    float* __restrict__ ho)
{
    __shared__ float agg[256];
    __shared__ float ewl[256];
    __shared__ int rl[256], cl[256];
    int n = blockIdx.x;
    int t = threadIdx.x;
    ewl[t] = ew[t];
    rl[t] = ei[t];
    cl[t] = ei[256 + t];
    __syncthreads();
    float a = 0.f;
    for (int e = 0; e < 256; e++)
        if (rl[e] == n) a += ewl[e] * h[cl[e] * 256 + t];
    agg[t] = a;
    __syncthreads();
    float o = 0.f;
    for (int c2 = 0; c2 < 256; c2++)
        o += agg[c2] * lw[t * 256 + c2];
    o += lb[t] + h[n * 256 + t];
    o = o > 0.f ? o : 0.f;
    ho[n * 256 + t] = o;
}

// ---------------- final fc: [64,256] @ [50,256]^T + b -> f32 out ----------------
__global__ void fc_k(const float* __restrict__ h, const float* __restrict__ fw,
                     const float* __restrict__ fb, float* __restrict__ out)
{
    int n = blockIdx.x;
    int t = threadIdx.x;
    if (t < 50) {
        float o = 0.f;
        for (int c = 0; c < 256; c++)
            o += h[n * 256 + c] * fw[t * 256 + c];
        o += fb[t];
        out[n * 50 + t] = o;
    }
}

extern "C" void kernel_launch(void* const* d_in, const int* in_sizes, int n_in,
                              void* d_out, int out_size, void* d_ws, size_t ws_size,
                              hipStream_t stream)
{
    (void)in_sizes; (void)n_in; (void)out_size;

    const float* X    = (const float*)d_in[0];
    const float* c1w  = (const float*)d_in[1];
    const float* c1b  = (const float*)d_in[2];
    const float* b1g  = (const float*)d_in[3];
    const float* b1b  = (const float*)d_in[4];
    const float* b1m  = (const float*)d_in[5];
    const float* b1v  = (const float*)d_in[6];
    const float* c2w  = (const float*)d_in[7];
    const float* c2b  = (const float*)d_in[8];
    const float* b2g  = (const float*)d_in[9];
    const float* b2b  = (const float*)d_in[10];
    const float* b2m  = (const float*)d_in[11];
    const float* b2v  = (const float*)d_in[12];
    const float* c3w  = (const float*)d_in[13];
    const float* c3b  = (const float*)d_in[14];
    const float* b3g  = (const float*)d_in[15];
    const float* b3b  = (const float*)d_in[16];
    const float* b3m  = (const float*)d_in[17];
    const float* b3v  = (const float*)d_in[18];
    const float* g1lw = (const float*)d_in[19];
    const float* g1lb = (const float*)d_in[20];
    const float* g1aw = (const float*)d_in[21];
    const float* g1ab = (const float*)d_in[22];
    const float* g2lw = (const float*)d_in[23];
    const float* g2lb = (const float*)d_in[24];
    const float* g2aw = (const float*)d_in[25];
    const float* g2ab = (const float*)d_in[26];
    const float* fcw  = (const float*)d_in[27];
    const float* fcb  = (const float*)d_in[28];
    const int*   EI   = (const int*)d_in[29];

    // runtime chunk size: largest of {64,32,16,8} that fits the workspace
    size_t fixedB = 3000000;
    int chb = 8;
    if (ws_size >= (size_t)64 * 5680128 + fixedB)      chb = 64;
    else if (ws_size >= (size_t)32 * 5680128 + fixedB) chb = 32;
    else if (ws_size >= (size_t)16 * 5680128 + fixedB) chb = 16;
    int nchunks = Bn / chb;
    int mch = chb * NPOS;                  // positions per chunk (div by 128)

    char* p = (char*)d_ws;
    auto carve = [&](size_t bytes) {
        char* r = p;
        p += (bytes + 255) & ~(size_t)255;
        return r;
    };
    __hip_bfloat16* h1c = (__hip_bfloat16*)carve((size_t)chb * HP * HP * C1c * 2);
    __hip_bfloat16* h2c = (__hip_bfloat16*)carve((size_t)chb * HP * HP * C2c * 2);
    __hip_bfloat16* wm2 = (__hip_bfloat16*)carve((size_t)9 * C1c * 256 * 2);
    __hip_bfloat16* wm3 = (__hip_bfloat16*)carve((size_t)9 * C2c * 256 * 2);
    float* sb2  = (float*)carve(512 * 4);
    float* sb3  = (float*)carve(512 * 4);
    float* pool = (float*)carve(64 * 256 * 4);
    float* h0   = (float*)carve(64 * 256 * 4);
    float* hg1  = (float*)carve(64 * 256 * 4);
    float* hg2  = (float*)carve(64 * 256 * 4);
    float* ew1  = (float*)carve(256 * 4);
    float* ew2  = (float*)carve(256 * 4);

    // prep (independent of conv outputs); halos stay zero across chunks/replays
    halo_zero<C1c><<<dim3(chb * 340), dim3(C1c), 0, stream>>>(h1c);
    halo_zero<C2c><<<dim3(chb * 340), dim3(C2c), 0, stream>>>(h2c);
    prep_w<C1c><<<dim3(9 * C1c), dim3(256), 0, stream>>>(c2w, wm2);
    prep_w<C2c><<<dim3(9 * C2c), dim3(256), 0, stream>>>(c3w, wm3);
    prep_sb<<<dim3(1), dim3(256), 0, stream>>>(c2b, b2g, b2b, b2m, b2v, sb2);
    prep_sb<<<dim3(1), dim3(256), 0, stream>>>(c3b, b3g, b3b, b3m, b3v, sb3);
    zero_f32<<<dim3(64), dim3(256), 0, stream>>>(pool);

    // conv chain, chunked over batch (chb images per chunk)
    for (int ch = 0; ch < nchunks; ch++) {
        const float* xch = X + (size_t)ch * chb * 3 * NPOS;
        conv1_k<<<dim3(chb * Hs), dim3(C1c), 0, stream>>>(
            xch, c1w, c1b, b1g, b1b, b1m, b1v, h1c);
        conv_igemm<C1c, false><<<dim3(mch / 128), dim3(512), 0, stream>>>(
            h1c, wm2, sb2, h2c, nullptr);
        conv_igemm<C2c, true ><<<dim3(mch / 128), dim3(512), 0, stream>>>(
            h2c, wm3, sb3, nullptr, pool + (size_t)ch * chb * 256);
    }
    pool_div<<<dim3(64), dim3(256), 0, stream>>>(pool, h0);

    // GCN layers + fc
    gcn_attn<<<dim3(1), dim3(256), 0, stream>>>(h0, g1aw, g1ab, EI, ew1);
    gcn_agg<<<dim3(64), dim3(256), 0, stream>>>(h0, ew1, EI, g1lw, g1lb, hg1);
    gcn_attn<<<dim3(1), dim3(256), 0, stream>>>(hg1, g2aw, g2ab, EI, ew2);
    gcn_agg<<<dim3(64), dim3(256), 0, stream>>>(hg1, ew2, EI, g2lw, g2lb, hg2);
    fc_k<<<dim3(64), dim3(64), 0, stream>>>(hg2, fcw, fcb, (float*)d_out);
}

// Round 11
// 1014.093 us; speedup vs baseline: 1.1554x; 1.0718x over previous
//
#include <hip/hip_runtime.h>
#include <hip/hip_bf16.h>

typedef __attribute__((ext_vector_type(8))) short bf16x8;
typedef __attribute__((ext_vector_type(4))) float f32x4;

#define DEV __device__ __forceinline__

static constexpr int Bn   = 64;
static constexpr int Hs   = 84;
static constexpr int HP   = 86;
static constexpr int C1c  = 128;
static constexpr int C2c  = 256;
static constexpr int NPOS = Hs * Hs;       // 7056
static constexpr float EPSf = 1e-5f;

DEV __hip_bfloat16 f2b(float v) { return __float2bfloat16(v); }

// async global(16B/lane) -> LDS (wave-uniform base + lane*16)
DEV void gload16(const void* g, void* l) {
    __builtin_amdgcn_global_load_lds(
        (const __attribute__((address_space(1))) void*)g,
        (__attribute__((address_space(3))) void*)l, 16, 0, 0);
}

// ---------------- conv1: 3->128 direct conv + BN + ReLU, f32 in -> padded NHWC bf16 (one chunk) ----------------
__global__ __launch_bounds__(128) void conv1_k(
    const float* __restrict__ x,   // chunk base: [chb,3,84,84] f32
    const float* __restrict__ w,  const float* __restrict__ cb,
    const float* __restrict__ g,  const float* __restrict__ be,
    const float* __restrict__ mm, const float* __restrict__ vv,
    __hip_bfloat16* __restrict__ h1)        // [chb,86,86,128]
{
    __shared__ float xin[3][3][HP];
    int bi = blockIdx.x;
    int b = bi / Hs, y = bi % Hs;
    int t = threadIdx.x;

    for (int idx = t; idx < 3 * 3 * HP; idx += 128) {
        int ci = idx / (3 * HP);
        int r  = idx % (3 * HP);
        int dy = r / HP;
        int xx = r % HP;
        int iy = y + dy - 1;
        int ix = xx - 1;
        float v = 0.f;
        if (iy >= 0 && iy < Hs && ix >= 0 && ix < Hs)
            v = x[((size_t)(b * 3 + ci) * Hs + iy) * Hs + ix];
        xin[ci][dy][xx] = v;
    }
    int co = t;
    float wr[3][3][3];
    for (int ci = 0; ci < 3; ci++)
        for (int dy = 0; dy < 3; dy++)
            for (int dx = 0; dx < 3; dx++)
                wr[ci][dy][dx] = w[((co * 3 + ci) * 3 + dy) * 3 + dx];
    float scale = g[co] / sqrtf(vv[co] + EPSf);
    float bias  = (cb[co] - mm[co]) * scale + be[co];
    __syncthreads();

    for (int xp = 0; xp < Hs; xp++) {
        float acc = 0.f;
        #pragma unroll
        for (int ci = 0; ci < 3; ci++)
            #pragma unroll
            for (int dy = 0; dy < 3; dy++)
                #pragma unroll
                for (int dx = 0; dx < 3; dx++)
                    acc += xin[ci][dy][xp + dx] * wr[ci][dy][dx];
        float o = acc * scale + bias;
        o = o > 0.f ? o : 0.f;
        h1[((size_t)(b * HP + y + 1) * HP + (xp + 1)) * C1c + co] = f2b(o);
    }
}

// ---------------- zero the 1px halo of a padded NHWC chunk buffer ----------------
template <int C>
__global__ void halo_zero(__hip_bfloat16* __restrict__ h)
{
    int i = blockIdx.x;
    int b = i / 340, p = i % 340;
    int y, xx;
    if (p < 86)       { y = 0;  xx = p; }
    else if (p < 172) { y = 85; xx = p - 86; }
    else if (p < 256) { xx = 0; y = p - 172 + 1; }
    else              { xx = 85; y = p - 256 + 1; }
    h[((size_t)(b * HP + y) * HP + xx) * C + threadIdx.x] = f2b(0.f);
}

// ---------------- repack conv weights OIHW f32 -> [K/32][256][32] bf16 (k = tap*CIN + ci) ----------------
template <int CIN>
__global__ void prep_w(const float* __restrict__ w, __hip_bfloat16* __restrict__ wm)
{
    int e  = blockIdx.x * 256 + threadIdx.x;   // over (9*CIN) * 256
    int k  = e >> 8;
    int co = e & 255;
    int tap = k / CIN;
    int ci  = k % CIN;
    int ty = tap / 3, tx = tap % 3;
    wm[(size_t)(k >> 5) * 8192 + co * 32 + (k & 31)] =
        f2b(w[((size_t)(co * CIN + ci) * 3 + ty) * 3 + tx]);
}

// ---------------- per-channel BN fold: sb[0:256]=scale, sb[256:512]=bias ----------------
__global__ void prep_sb(const float* __restrict__ cb, const float* __restrict__ g,
                        const float* __restrict__ be, const float* __restrict__ mm,
                        const float* __restrict__ vv, float* __restrict__ sb)
{
    int co = threadIdx.x;
    float s = g[co] / sqrtf(vv[co] + EPSf);
    sb[co] = s;
    sb[256 + co] = (cb[co] - mm[co]) * s + be[co];
}

__global__ void zero_f32(float* __restrict__ p)
{
    p[blockIdx.x * 256 + threadIdx.x] = 0.f;
}

// ---------------- 8-phase pipelined implicit-GEMM conv (3x3 SAME) ----------------
// Identical to R10 EXCEPT: XOR-swizzled LDS restored (T2). Staging source seg
// pre-swizzled seg' = (t&3) ^ ((t>>3)&3) (LDS dest linear, m104/m173); reads use
// (lg ^ ((lidx>>1)&3))*16. Involution: slot c of row r holds src seg c^((r>>1)&3);
// all fragment rows have row-bits-1..2 = (lidx>>1)&3. 2 lanes/bank-quad = free.
template <int CIN, bool POOL>
__global__ __launch_bounds__(512, 2) void conv_igemm(
    const __hip_bfloat16* __restrict__ in, const __hip_bfloat16* __restrict__ wgt,
    const float* __restrict__ sb, __hip_bfloat16* __restrict__ out, float* __restrict__ pool)
{
    constexpr int KB = CIN / 32;
    constexpr int NK = 9 * KB / 2;             // K-tiles of 64 (18 or 36)
    constexpr unsigned BUF = 49152u;           // 48 KB per buffer
    __shared__ __align__(16) char lds[3 * 49152];
    __shared__ float pl[512];

    int t = threadIdx.x;
    int l = t & 63, w = t >> 6;                // 8 waves
    int lidx = l & 15, lg = l >> 4;
    int wm = w >> 2, wn = w & 3;               // wave tile: rows wm*64.., cols wn*64..

    // bijective XCD-aware swizzle (m204)
    int nwg  = (int)gridDim.x;
    int orig = (int)blockIdx.x;
    int xcd = orig & 7, idx = orig >> 3;
    int q = nwg >> 3, r = nwg & 7;
    int bx = (xcd < r ? xcd * (q + 1) : r * (q + 1) + (xcd - r) * q) + idx;
    int m0 = bx * 128;

    // ---- staging lane sources: lane t stages row (t>>2), PRE-SWIZZLED seg ----
    int seg  = (t & 3) ^ ((t >> 3) & 3);       // involution w/ row bits 1-2
    int srow = t >> 2;                         // 0..127
    const __hip_bfloat16* pA;
    {
        int gm = m0 + srow;
        int b0 = gm / NPOS; int r0 = gm - b0 * NPOS;
        int y0 = r0 / Hs;   int x0 = r0 - y0 * Hs;
        pA = in + ((size_t)(b0 * HP + y0) * HP + x0) * CIN + seg * 8;
    }
    const __hip_bfloat16* pB = wgt + (size_t)srow * 32 + seg * 8;

    // ---- frag ds_read byte offsets (within one 48 KB buffer, swizzled) ----
    int swz = (lidx >> 1) & 3;
    unsigned aRd[4][2], bRd[4][2];
    #pragma unroll
    for (int mf = 0; mf < 4; mf++)
        #pragma unroll
        for (int kh = 0; kh < 2; kh++)
            aRd[mf][kh] = (unsigned)(kh * 8192 + (wm * 64 + mf * 16 + lidx) * 64 + ((lg ^ swz) * 16));
    #pragma unroll
    for (int nf = 0; nf < 4; nf++)
        #pragma unroll
        for (int kh = 0; kh < 2; kh++)
            bRd[nf][kh] = (unsigned)(16384 + kh * 16384 + (wn * 64 + nf * 16 + lidx) * 64 + ((lg ^ swz) * 16));

    f32x4 acc[4][4];
    #pragma unroll
    for (int i = 0; i < 4; i++)
        #pragma unroll
        for (int j = 0; j < 4; j++)
            acc[i][j] = (f32x4){0.f, 0.f, 0.f, 0.f};
    if (POOL) pl[t] = 0.f;

    // sub-step s -> (kb = s/9 OUTER, tap = s%9 INNER): L2 locality (R6/R8 lesson)
    auto AOFF = [&](int s) -> size_t {
        int kb = s / 9, tap = s - kb * 9;
        int ty = tap / 3, tx = tap - ty * 3;
        return (size_t)(ty * HP + tx) * CIN + kb * 32;
    };
    auto BOFF = [&](int s) -> size_t {
        int kb = s / 9, tap = s - kb * 9;
        return (size_t)(tap * KB + kb) * 8192;
    };
    // phase-0 staging of K-tile kt2 into buffer nb: A kh0, A kh1, B kh0 lo
    auto ISSUE_P0 = [&](int kt2, unsigned nb) {
        int s0 = 2 * kt2, s1 = s0 + 1;
        gload16(pA + AOFF(s0), lds + nb +          w * 1024);
        gload16(pA + AOFF(s1), lds + nb +  8192 + w * 1024);
        gload16(pB + BOFF(s0), lds + nb + 16384 + w * 1024);
    };
    // phase-1 staging: B kh0 hi, B kh1 lo, B kh1 hi
    auto ISSUE_P1 = [&](int kt2, unsigned nb) {
        int s0 = 2 * kt2, s1 = s0 + 1;
        gload16(pB + BOFF(s0) + 4096, lds + nb + 24576 + w * 1024);
        gload16(pB + BOFF(s1),        lds + nb + 32768 + w * 1024);
        gload16(pB + BOFF(s1) + 4096, lds + nb + 40960 + w * 1024);
    };

    // prologue: stage K-tiles 0 and 1 (12 loads in flight)
    ISSUE_P0(0, 0u); ISSUE_P1(0, 0u);
    ISSUE_P0(1, BUF); ISSUE_P1(1, BUF);

    for (int kt = 0; kt < NK; ++kt) {
        unsigned cb = (unsigned)(kt % 3) * BUF;
        unsigned nb = (unsigned)((kt + 2) % 3) * BUF;
        bool more = (kt + 2) < NK;

        // ===== phase 0: A all + B nf 0,1 =====
        if (kt + 1 < NK) asm volatile("s_waitcnt vmcnt(6)" ::: "memory");
        else             asm volatile("s_waitcnt vmcnt(0)" ::: "memory");
        __builtin_amdgcn_s_barrier();   // all waves' kt loads landed

        bf16x8 av[4][2], bv0[2][2];
        #pragma unroll
        for (int mf = 0; mf < 4; mf++)
            #pragma unroll
            for (int kh = 0; kh < 2; kh++)
                av[mf][kh] = *(const bf16x8*)(lds + cb + aRd[mf][kh]);
        #pragma unroll
        for (int nf = 0; nf < 2; nf++)
            #pragma unroll
            for (int kh = 0; kh < 2; kh++)
                bv0[nf][kh] = *(const bf16x8*)(lds + cb + bRd[nf][kh]);
        if (more) ISSUE_P0(kt + 2, nb);
        __builtin_amdgcn_s_barrier();
        asm volatile("s_waitcnt lgkmcnt(0)" ::: "memory");
        __builtin_amdgcn_sched_barrier(0);
        __builtin_amdgcn_s_setprio(1);
        #pragma unroll
        for (int kh = 0; kh < 2; kh++)
            #pragma unroll
            for (int mf = 0; mf < 4; mf++)
                #pragma unroll
                for (int nf = 0; nf < 2; nf++)
                    acc[mf][nf] = __builtin_amdgcn_mfma_f32_16x16x32_bf16(
                        av[mf][kh], bv0[nf][kh], acc[mf][nf], 0, 0, 0);
        __builtin_amdgcn_s_setprio(0);

        // ===== phase 1: A held + B nf 2,3 =====
        __builtin_amdgcn_s_barrier();
        bf16x8 bv1[2][2];
        #pragma unroll
        for (int nf = 0; nf < 2; nf++)
            #pragma unroll
            for (int kh = 0; kh < 2; kh++)
                bv1[nf][kh] = *(const bf16x8*)(lds + cb + bRd[2 + nf][kh]);
        if (more) ISSUE_P1(kt + 2, nb);
        __builtin_amdgcn_s_barrier();
        asm volatile("s_waitcnt lgkmcnt(0)" ::: "memory");
        __builtin_amdgcn_sched_barrier(0);
        __builtin_amdgcn_s_setprio(1);
        #pragma unroll
        for (int kh = 0; kh < 2; kh++)
            #pragma unroll
            for (int mf = 0; mf < 4; mf++)
                #pragma unroll
                for (int nf = 0; nf < 2; nf++)
                    acc[mf][2 + nf] = __builtin_amdgcn_mfma_f32_16x16x32_bf16(
                        av[mf][kh], bv1[nf][kh], acc[mf][2 + nf], 0, 0, 0);
        __builtin_amdgcn_s_setprio(0);
    }

    // ---- epilogue ----
    float sc[4], bi2[4];
    #pragma unroll
    for (int nf = 0; nf < 4; nf++) {
        int cn = wn * 64 + nf * 16 + lidx;
        sc[nf]  = sb[cn];
        bi2[nf] = sb[256 + cn];
    }

    if (!POOL) {
        #pragma unroll
        for (int mf = 0; mf < 4; mf++) {
            #pragma unroll
            for (int r2 = 0; r2 < 4; r2++) {
                int row = wm * 64 + mf * 16 + lg * 4 + r2;
                int gm2 = m0 + row;
                int b2  = gm2 / NPOS;
                int rm2 = gm2 - b2 * NPOS;
                int y2  = rm2 / Hs;
                int x2  = rm2 - y2 * Hs;
                size_t ob = ((size_t)(b2 * HP + y2 + 1) * HP + (x2 + 1)) * 256;
                #pragma unroll
                for (int nf = 0; nf < 4; nf++) {
                    float v = acc[mf][nf][r2] * sc[nf] + bi2[nf];
                    v = v > 0.f ? v : 0.f;
                    out[ob + wn * 64 + nf * 16 + lidx] = f2b(v);
                }
            }
        }
    } else {
        int bs_lo   = m0 / NPOS;
        int row_lim = (bs_lo + 1) * NPOS - m0;  // rows >= row_lim belong to image bs_lo+1
        __builtin_amdgcn_s_barrier();            // pl[] init visible (redundant w/ loop barriers)
        #pragma unroll
        for (int nf = 0; nf < 4; nf++) {
            float s0 = 0.f, s1 = 0.f;
            #pragma unroll
            for (int mf = 0; mf < 4; mf++)
                #pragma unroll
                for (int r2 = 0; r2 < 4; r2++) {
                    int row = wm * 64 + mf * 16 + lg * 4 + r2;
                    float v = acc[mf][nf][r2] * sc[nf] + bi2[nf];
                    v = v > 0.f ? v : 0.f;
                    if (row < row_lim) s0 += v; else s1 += v;
                }
            int cl = wn * 64 + nf * 16 + lidx;   // [0,256)
            atomicAdd(&pl[cl], s0);
            if (row_lim < 128) atomicAdd(&pl[256 + cl], s1);
        }
        __syncthreads();
        if (t < 256)
            atomicAdd(&pool[bs_lo * 256 + t], pl[t]);
        else if (row_lim < 128)
            atomicAdd(&pool[(bs_lo + 1) * 256 + (t - 256)], pl[t]);
    }
}

// ---------------- pool finalize: mean ----------------
__global__ void pool_div(const float* __restrict__ pool, float* __restrict__ h0)
{
    int i = blockIdx.x * 256 + threadIdx.x;
    h0[i] = pool[i] * (1.0f / (float)NPOS);
}

// ---------------- GCN attention: ew = softmax(leaky(p[row]+q[col]+ab)) over 256 edges ----------------
__global__ __launch_bounds__(256) void gcn_attn(
    const float* __restrict__ h, const float* __restrict__ aw,
    const float* __restrict__ ab, const int* __restrict__ ei,
    float* __restrict__ ew)
{
    __shared__ float p[64], q[64], red[256];
    int t = threadIdx.x;
    if (t < 64) {
        float pp = 0.f, qq = 0.f;
        for (int c = 0; c < 256; c++) {
            float hv = h[t * 256 + c];
            pp += hv * aw[c];
            qq += hv * aw[256 + c];
        }
        p[t] = pp; q[t] = qq;
    }
    __syncthreads();
    int r = ei[t], c = ei[256 + t];
    float s = p[r] + q[c] + ab[0];
    s = s >= 0.f ? s : 0.01f * s;
    red[t] = s;
    __syncthreads();
    for (int st = 128; st > 0; st >>= 1) {
        if (t < st) red[t] = fmaxf(red[t], red[t + st]);
        __syncthreads();
    }
    float mx = red[0];
    __syncthreads();
    float e = expf(s - mx);
    red[t] = e;
    __syncthreads();
    for (int st = 128; st > 0; st >>= 1) {
        if (t < st) red[t] += red[t + st];
        __syncthreads();
    }
    ew[t] = e / red[0];
}

// ---------------- GCN aggregate + linear + residual (+ReLU) ----------------
__global__ __launch_bounds__(256) void gcn_agg(
    const float* __restrict__ h, const float* __restrict__ ew, const int* __restrict__ ei,
    const float* __restrict__ lw, const float* __restrict__ lb,
    float* __restrict__ ho)
{
    __shared__ float agg[256];
    __shared__ float ewl[256];
    __shared__ int rl[256], cl[256];
    int n = blockIdx.x;
    int t = threadIdx.x;
    ewl[t] = ew[t];
    rl[t] = ei[t];
    cl[t] = ei[256 + t];
    __syncthreads();
    float a = 0.f;
    for (int e = 0; e < 256; e++)
        if (rl[e] == n) a += ewl[e] * h[cl[e] * 256 + t];
    agg[t] = a;
    __syncthreads();
    float o = 0.f;
    for (int c2 = 0; c2 < 256; c2++)
        o += agg[c2] * lw[t * 256 + c2];
    o += lb[t] + h[n * 256 + t];
    o = o > 0.f ? o : 0.f;
    ho[n * 256 + t] = o;
}

// ---------------- final fc: [64,256] @ [50,256]^T + b -> f32 out ----------------
__global__ void fc_k(const float* __restrict__ h, const float* __restrict__ fw,
                     const float* __restrict__ fb, float* __restrict__ out)
{
    int n = blockIdx.x;
    int t = threadIdx.x;
    if (t < 50) {
        float o = 0.f;
        for (int c = 0; c < 256; c++)
            o += h[n * 256 + c] * fw[t * 256 + c];
        o += fb[t];
        out[n * 50 + t] = o;
    }
}

extern "C" void kernel_launch(void* const* d_in, const int* in_sizes, int n_in,
                              void* d_out, int out_size, void* d_ws, size_t ws_size,
                              hipStream_t stream)
{
    (void)in_sizes; (void)n_in; (void)out_size;

    const float* X    = (const float*)d_in[0];
    const float* c1w  = (const float*)d_in[1];
    const float* c1b  = (const float*)d_in[2];
    const float* b1g  = (const float*)d_in[3];
    const float* b1b  = (const float*)d_in[4];
    const float* b1m  = (const float*)d_in[5];
    const float* b1v  = (const float*)d_in[6];
    const float* c2w  = (const float*)d_in[7];
    const float* c2b  = (const float*)d_in[8];
    const float* b2g  = (const float*)d_in[9];
    const float* b2b  = (const float*)d_in[10];
    const float* b2m  = (const float*)d_in[11];
    const float* b2v  = (const float*)d_in[12];
    const float* c3w  = (const float*)d_in[13];
    const float* c3b  = (const float*)d_in[14];
    const float* b3g  = (const float*)d_in[15];
    const float* b3b  = (const float*)d_in[16];
    const float* b3m  = (const float*)d_in[17];
    const float* b3v  = (const float*)d_in[18];
    const float* g1lw = (const float*)d_in[19];
    const float* g1lb = (const float*)d_in[20];
    const float* g1aw = (const float*)d_in[21];
    const float* g1ab = (const float*)d_in[22];
    const float* g2lw = (const float*)d_in[23];
    const float* g2lb = (const float*)d_in[24];
    const float* g2aw = (const float*)d_in[25];
    const float* g2ab = (const float*)d_in[26];
    const float* fcw  = (const float*)d_in[27];
    const float* fcb  = (const float*)d_in[28];
    const int*   EI   = (const int*)d_in[29];

    // runtime chunk size: largest of {64,32,16,8} that fits the workspace
    size_t fixedB = 3000000;
    int chb = 8;
    if (ws_size >= (size_t)64 * 5680128 + fixedB)      chb = 64;
    else if (ws_size >= (size_t)32 * 5680128 + fixedB) chb = 32;
    else if (ws_size >= (size_t)16 * 5680128 + fixedB) chb = 16;
    int nchunks = Bn / chb;
    int mch = chb * NPOS;                  // positions per chunk (div by 128)

    char* p = (char*)d_ws;
    auto carve = [&](size_t bytes) {
        char* r = p;
        p += (bytes + 255) & ~(size_t)255;
        return r;
    };
    __hip_bfloat16* h1c = (__hip_bfloat16*)carve((size_t)chb * HP * HP * C1c * 2);
    __hip_bfloat16* h2c = (__hip_bfloat16*)carve((size_t)chb * HP * HP * C2c * 2);
    __hip_bfloat16* wm2 = (__hip_bfloat16*)carve((size_t)9 * C1c * 256 * 2);
    __hip_bfloat16* wm3 = (__hip_bfloat16*)carve((size_t)9 * C2c * 256 * 2);
    float* sb2  = (float*)carve(512 * 4);
    float* sb3  = (float*)carve(512 * 4);
    float* pool = (float*)carve(64 * 256 * 4);
    float* h0   = (float*)carve(64 * 256 * 4);
    float* hg1  = (float*)carve(64 * 256 * 4);
    float* hg2  = (float*)carve(64 * 256 * 4);
    float* ew1  = (float*)carve(256 * 4);
    float* ew2  = (float*)carve(256 * 4);

    // prep (independent of conv outputs); halos stay zero across chunks/replays
    halo_zero<C1c><<<dim3(chb * 340), dim3(C1c), 0, stream>>>(h1c);
    halo_zero<C2c><<<dim3(chb * 340), dim3(C2c), 0, stream>>>(h2c);
    prep_w<C1c><<<dim3(9 * C1c), dim3(256), 0, stream>>>(c2w, wm2);
    prep_w<C2c><<<dim3(9 * C2c), dim3(256), 0, stream>>>(c3w, wm3);
    prep_sb<<<dim3(1), dim3(256), 0, stream>>>(c2b, b2g, b2b, b2m, b2v, sb2);
    prep_sb<<<dim3(1), dim3(256), 0, stream>>>(c3b, b3g, b3b, b3m, b3v, sb3);
    zero_f32<<<dim3(64), dim3(256), 0, stream>>>(pool);

    // conv chain, chunked over batch (chb images per chunk)
    for (int ch = 0; ch < nchunks; ch++) {
        const float* xch = X + (size_t)ch * chb * 3 * NPOS;
        conv1_k<<<dim3(chb * Hs), dim3(C1c), 0, stream>>>(
            xch, c1w, c1b, b1g, b1b, b1m, b1v, h1c);
        conv_igemm<C1c, false><<<dim3(mch / 128), dim3(512), 0, stream>>>(
            h1c, wm2, sb2, h2c, nullptr);
        conv_igemm<C2c, true ><<<dim3(mch / 128), dim3(512), 0, stream>>>(
            h2c, wm3, sb3, nullptr, pool + (size_t)ch * chb * 256);
    }
    pool_div<<<dim3(64), dim3(256), 0, stream>>>(pool, h0);

    // GCN layers + fc
    gcn_attn<<<dim3(1), dim3(256), 0, stream>>>(h0, g1aw, g1ab, EI, ew1);
    gcn_agg<<<dim3(64), dim3(256), 0, stream>>>(h0, ew1, EI, g1lw, g1lb, hg1);
    gcn_attn<<<dim3(1), dim3(256), 0, stream>>>(hg1, g2aw, g2ab, EI, ew2);
    gcn_agg<<<dim3(64), dim3(256), 0, stream>>>(hg1, ew2, EI, g2lw, g2lb, hg2);
    fc_k<<<dim3(64), dim3(64), 0, stream>>>(hg2, fcw, fcb, (float*)d_out);
}

// Round 12
// 1007.171 us; speedup vs baseline: 1.1634x; 1.0069x over previous
//
#include <hip/hip_runtime.h>
#include <hip/hip_bf16.h>

typedef __attribute__((ext_vector_type(8))) short bf16x8;
typedef __attribute__((ext_vector_type(4))) float f32x4;

#define DEV __device__ __forceinline__

static constexpr int Bn   = 64;
static constexpr int Hs   = 84;
static constexpr int HP   = 86;
static constexpr int C1c  = 128;
static constexpr int C2c  = 256;
static constexpr int NPOS = Hs * Hs;       // 7056
static constexpr float EPSf = 1e-5f;

DEV __hip_bfloat16 f2b(float v) { return __float2bfloat16(v); }

// async global(16B/lane) -> LDS (wave-uniform base + lane*16)
DEV void gload16(const void* g, void* l) {
    __builtin_amdgcn_global_load_lds(
        (const __attribute__((address_space(1))) void*)g,
        (__attribute__((address_space(3))) void*)l, 16, 0, 0);
}

// ---------------- conv1: 3->128 direct conv + BN + ReLU, f32 in -> padded NHWC bf16 (one chunk) ----------------
__global__ __launch_bounds__(128) void conv1_k(
    const float* __restrict__ x,   // chunk base: [chb,3,84,84] f32
    const float* __restrict__ w,  const float* __restrict__ cb,
    const float* __restrict__ g,  const float* __restrict__ be,
    const float* __restrict__ mm, const float* __restrict__ vv,
    __hip_bfloat16* __restrict__ h1)        // [chb,86,86,128]
{
    __shared__ float xin[3][3][HP];
    int bi = blockIdx.x;
    int b = bi / Hs, y = bi % Hs;
    int t = threadIdx.x;

    for (int idx = t; idx < 3 * 3 * HP; idx += 128) {
        int ci = idx / (3 * HP);
        int r  = idx % (3 * HP);
        int dy = r / HP;
        int xx = r % HP;
        int iy = y + dy - 1;
        int ix = xx - 1;
        float v = 0.f;
        if (iy >= 0 && iy < Hs && ix >= 0 && ix < Hs)
            v = x[((size_t)(b * 3 + ci) * Hs + iy) * Hs + ix];
        xin[ci][dy][xx] = v;
    }
    int co = t;
    float wr[3][3][3];
    for (int ci = 0; ci < 3; ci++)
        for (int dy = 0; dy < 3; dy++)
            for (int dx = 0; dx < 3; dx++)
                wr[ci][dy][dx] = w[((co * 3 + ci) * 3 + dy) * 3 + dx];
    float scale = g[co] / sqrtf(vv[co] + EPSf);
    float bias  = (cb[co] - mm[co]) * scale + be[co];
    __syncthreads();

    for (int xp = 0; xp < Hs; xp++) {
        float acc = 0.f;
        #pragma unroll
        for (int ci = 0; ci < 3; ci++)
            #pragma unroll
            for (int dy = 0; dy < 3; dy++)
                #pragma unroll
                for (int dx = 0; dx < 3; dx++)
                    acc += xin[ci][dy][xp + dx] * wr[ci][dy][dx];
        float o = acc * scale + bias;
        o = o > 0.f ? o : 0.f;
        h1[((size_t)(b * HP + y + 1) * HP + (xp + 1)) * C1c + co] = f2b(o);
    }
}

// ---------------- zero the 1px halo of a padded NHWC chunk buffer ----------------
template <int C>
__global__ void halo_zero(__hip_bfloat16* __restrict__ h)
{
    int i = blockIdx.x;
    int b = i / 340, p = i % 340;
    int y, xx;
    if (p < 86)       { y = 0;  xx = p; }
    else if (p < 172) { y = 85; xx = p - 86; }
    else if (p < 256) { xx = 0; y = p - 172 + 1; }
    else              { xx = 85; y = p - 256 + 1; }
    h[((size_t)(b * HP + y) * HP + xx) * C + threadIdx.x] = f2b(0.f);
}

// ---------------- repack conv weights OIHW f32 -> [K/32][256][32] bf16 (k = tap*CIN + ci) ----------------
template <int CIN>
__global__ void prep_w(const float* __restrict__ w, __hip_bfloat16* __restrict__ wm)
{
    int e  = blockIdx.x * 256 + threadIdx.x;   // over (9*CIN) * 256
    int k  = e >> 8;
    int co = e & 255;
    int tap = k / CIN;
    int ci  = k % CIN;
    int ty = tap / 3, tx = tap % 3;
    wm[(size_t)(k >> 5) * 8192 + co * 32 + (k & 31)] =
        f2b(w[((size_t)(co * CIN + ci) * 3 + ty) * 3 + tx]);
}

// ---------------- per-channel BN fold: sb[0:256]=scale, sb[256:512]=bias ----------------
__global__ void prep_sb(const float* __restrict__ cb, const float* __restrict__ g,
                        const float* __restrict__ be, const float* __restrict__ mm,
                        const float* __restrict__ vv, float* __restrict__ sb)
{
    int co = threadIdx.x;
    float s = g[co] / sqrtf(vv[co] + EPSf);
    sb[co] = s;
    sb[256 + co] = (cb[co] - mm[co]) * s + be[co];
}

__global__ void zero_f32(float* __restrict__ p)
{
    p[blockIdx.x * 256 + threadIdx.x] = 0.f;
}

// ---------------- 256x256 8-phase pipelined implicit-GEMM conv (3x3 SAME) ----------------
// BM=256, BN=256, BK=64 (2 sub-steps of 32); 512 thr / 8 waves (2M x 4N, wave 128x64).
// Double-buffered LDS (2 x 64 KB), kh-half prefetch granularity, counted vmcnt(4)
// (never 0 until last tile). Per K-tile 4 phases: {vmcnt?; bar; ds_reads + issue
// one kh-half (4 gloads); bar; lgkmcnt(0); 16 MFMA}. B frags reused across m-halves.
// LDS planes per buffer: A_kh0 @0, A_kh1 @16K, B_kh0 @32K, B_kh1 @48K; 64B rows,
// R11 involution swizzle (measured 0 conflicts). kb-outer/tap-inner K order.
// grid.x = chb*NPOS/256, block = 512.
template <int CIN, bool POOL>
__global__ __launch_bounds__(512, 2) void conv_igemm(
    const __hip_bfloat16* __restrict__ in, const __hip_bfloat16* __restrict__ wgt,
    const float* __restrict__ sb, __hip_bfloat16* __restrict__ out, float* __restrict__ pool)
{
    constexpr int KB = CIN / 32;
    constexpr int NK = 9 * KB / 2;             // K-tiles of 64 (18 or 36)
    constexpr unsigned BUFSZ = 65536u;         // 64 KB per buffer
    __shared__ __align__(16) char lds[2 * 65536];
    __shared__ float pl[512];

    int t = threadIdx.x;
    int l = t & 63, w = t >> 6;                // 8 waves
    int lidx = l & 15, lg = l >> 4;
    int wm = w >> 2, wn = w & 3;               // wave tile: rows wm*128.., cols wn*64..

    // bijective XCD-aware swizzle (m204)
    int nwg  = (int)gridDim.x;
    int orig = (int)blockIdx.x;
    int xcd = orig & 7, idx = orig >> 3;
    int q = nwg >> 3, r = nwg & 7;
    int bx = (xcd < r ? xcd * (q + 1) : r * (q + 1) + (xcd - r) * q) + idx;
    int m0 = bx * 256;

    // ---- staging lane sources: lane t stages rows (t>>2) and (t>>2)+128, PRE-SWIZZLED seg ----
    int seg  = (t & 3) ^ ((t >> 3) & 3);       // involution w/ row bits 1-2 (row = t>>2)
    int srow = t >> 2;                         // 0..127
    const __hip_bfloat16 *pA0, *pA1;
    {
        int gm = m0 + srow;
        int b0 = gm / NPOS; int r0 = gm - b0 * NPOS;
        int y0 = r0 / Hs;   int x0 = r0 - y0 * Hs;
        pA0 = in + ((size_t)(b0 * HP + y0) * HP + x0) * CIN + seg * 8;
        gm = m0 + 128 + srow;
        b0 = gm / NPOS; r0 = gm - b0 * NPOS;
        y0 = r0 / Hs;   x0 = r0 - y0 * Hs;
        pA1 = in + ((size_t)(b0 * HP + y0) * HP + x0) * CIN + seg * 8;
    }
    const __hip_bfloat16* pB0 = wgt + (size_t)srow * 32 + seg * 8;
    const __hip_bfloat16* pB1 = wgt + (size_t)(128 + srow) * 32 + seg * 8;

    // ---- frag ds_read byte offsets (within one 64 KB buffer, swizzled) ----
    int swz = (lidx >> 1) & 3;
    unsigned aRd[8][2], bRd[4][2];
    #pragma unroll
    for (int mf = 0; mf < 8; mf++)
        #pragma unroll
        for (int kh = 0; kh < 2; kh++)
            aRd[mf][kh] = (unsigned)(kh * 16384 + (wm * 128 + mf * 16 + lidx) * 64 + ((lg ^ swz) * 16));
    #pragma unroll
    for (int nf = 0; nf < 4; nf++)
        #pragma unroll
        for (int kh = 0; kh < 2; kh++)
            bRd[nf][kh] = (unsigned)(32768 + kh * 16384 + (wn * 64 + nf * 16 + lidx) * 64 + ((lg ^ swz) * 16));

    f32x4 acc[8][4];
    #pragma unroll
    for (int i = 0; i < 8; i++)
        #pragma unroll
        for (int j = 0; j < 4; j++)
            acc[i][j] = (f32x4){0.f, 0.f, 0.f, 0.f};
    if (POOL) pl[t] = 0.f;

    // sub-step s -> (kb = s/9 OUTER, tap = s%9 INNER): L2 locality (R6/R8 lesson)
    auto AOFF = [&](int s) -> size_t {
        int kb = s / 9, tap = s - kb * 9;
        int ty = tap / 3, tx = tap - ty * 3;
        return (size_t)(ty * HP + tx) * CIN + kb * 32;
    };
    auto BOFF = [&](int s) -> size_t {
        int kb = s / 9, tap = s - kb * 9;
        return (size_t)(tap * KB + kb) * 8192;
    };
    // stage kh-half of K-tile kt2 into buffer base bb (4 gloads = A 16KB + B 16KB)
    auto ISSUE = [&](int kt2, int kh, unsigned bb) {
        int s = 2 * kt2 + kh;
        size_t ao = AOFF(s), bo = BOFF(s);
        unsigned ap = bb + (unsigned)(kh * 16384) + (unsigned)(w * 1024);
        unsigned bp = bb + 32768u + (unsigned)(kh * 16384) + (unsigned)(w * 1024);
        gload16(pA0 + ao, lds + ap);
        gload16(pA1 + ao, lds + ap + 8192);
        gload16(pB0 + bo, lds + bp);
        gload16(pB1 + bo, lds + bp + 8192);
    };

    // prologue: stage both halves of K-tile 0 (8 loads in flight)
    ISSUE(0, 0, 0u);
    ISSUE(0, 1, 0u);

    for (int kt = 0; kt < NK; ++kt) {
        unsigned cb = (kt & 1) ? BUFSZ : 0u;
        unsigned nb = (kt & 1) ? 0u : BUFSZ;
        bool more = (kt + 1) < NK;

        #pragma unroll
        for (int kh = 0; kh < 2; ++kh) {
            // ===== phase A: m-half 0 + B[kh] =====
            if (kh == 0 || more) asm volatile("s_waitcnt vmcnt(4)" ::: "memory");
            else                 asm volatile("s_waitcnt vmcnt(0)" ::: "memory");
            __builtin_amdgcn_s_barrier();   // kh-half of tile kt landed for all waves

            bf16x8 av[4], bv[4];
            #pragma unroll
            for (int mf = 0; mf < 4; mf++)
                av[mf] = *(const bf16x8*)(lds + cb + aRd[mf][kh]);
            #pragma unroll
            for (int nf = 0; nf < 4; nf++)
                bv[nf] = *(const bf16x8*)(lds + cb + bRd[nf][kh]);
            if (more) ISSUE(kt + 1, kh, nb);
            __builtin_amdgcn_s_barrier();
            asm volatile("s_waitcnt lgkmcnt(0)" ::: "memory");
            __builtin_amdgcn_sched_barrier(0);
            __builtin_amdgcn_s_setprio(1);
            #pragma unroll
            for (int mf = 0; mf < 4; mf++)
                #pragma unroll
                for (int nf = 0; nf < 4; nf++)
                    acc[mf][nf] = __builtin_amdgcn_mfma_f32_16x16x32_bf16(
                        av[mf], bv[nf], acc[mf][nf], 0, 0, 0);
            __builtin_amdgcn_s_setprio(0);

            // ===== phase B: m-half 1, reuse bv =====
            __builtin_amdgcn_s_barrier();
            bf16x8 av2[4];
            #pragma unroll
            for (int mf = 0; mf < 4; mf++)
                av2[mf] = *(const bf16x8*)(lds + cb + aRd[4 + mf][kh]);
            __builtin_amdgcn_s_barrier();
            asm volatile("s_waitcnt lgkmcnt(0)" ::: "memory");
            __builtin_amdgcn_sched_barrier(0);
            __builtin_amdgcn_s_setprio(1);
            #pragma unroll
            for (int mf = 0; mf < 4; mf++)
                #pragma unroll
                for (int nf = 0; nf < 4; nf++)
                    acc[4 + mf][nf] = __builtin_amdgcn_mfma_f32_16x16x32_bf16(
                        av2[mf], bv[nf], acc[4 + mf][nf], 0, 0, 0);
            __builtin_amdgcn_s_setprio(0);
        }
    }

    // ---- epilogue ----
    float sc[4], bi2[4];
    #pragma unroll
    for (int nf = 0; nf < 4; nf++) {
        int cn = wn * 64 + nf * 16 + lidx;
        sc[nf]  = sb[cn];
        bi2[nf] = sb[256 + cn];
    }

    if (!POOL) {
        #pragma unroll
        for (int mf = 0; mf < 8; mf++) {
            #pragma unroll
            for (int r2 = 0; r2 < 4; r2++) {
                int row = wm * 128 + mf * 16 + lg * 4 + r2;
                int gm2 = m0 + row;
                int b2  = gm2 / NPOS;
                int rm2 = gm2 - b2 * NPOS;
                int y2  = rm2 / Hs;
                int x2  = rm2 - y2 * Hs;
                size_t ob = ((size_t)(b2 * HP + y2 + 1) * HP + (x2 + 1)) * 256;
                #pragma unroll
                for (int nf = 0; nf < 4; nf++) {
                    float v = acc[mf][nf][r2] * sc[nf] + bi2[nf];
                    v = v > 0.f ? v : 0.f;
                    out[ob + wn * 64 + nf * 16 + lidx] = f2b(v);
                }
            }
        }
    } else {
        int bs_lo   = m0 / NPOS;
        int row_lim = (bs_lo + 1) * NPOS - m0;  // rows >= row_lim belong to image bs_lo+1
        __builtin_amdgcn_s_barrier();            // pl[] init visible
        #pragma unroll
        for (int nf = 0; nf < 4; nf++) {
            float s0 = 0.f, s1 = 0.f;
            #pragma unroll
            for (int mf = 0; mf < 8; mf++)
                #pragma unroll
                for (int r2 = 0; r2 < 4; r2++) {
                    int row = wm * 128 + mf * 16 + lg * 4 + r2;
                    float v = acc[mf][nf][r2] * sc[nf] + bi2[nf];
                    v = v > 0.f ? v : 0.f;
                    if (row < row_lim) s0 += v; else s1 += v;
                }
            int cl = wn * 64 + nf * 16 + lidx;   // [0,256)
            atomicAdd(&pl[cl], s0);
            if (row_lim < 256) atomicAdd(&pl[256 + cl], s1);
        }
        __syncthreads();
        if (t < 256)
            atomicAdd(&pool[bs_lo * 256 + t], pl[t]);
        else if (row_lim < 256)
            atomicAdd(&pool[(bs_lo + 1) * 256 + (t - 256)], pl[t]);
    }
}

// ---------------- pool finalize: mean ----------------
__global__ void pool_div(const float* __restrict__ pool, float* __restrict__ h0)
{
    int i = blockIdx.x * 256 + threadIdx.x;
    h0[i] = pool[i] * (1.0f / (float)NPOS);
}

// ---------------- GCN attention: ew = softmax(leaky(p[row]+q[col]+ab)) over 256 edges ----------------
__global__ __launch_bounds__(256) void gcn_attn(
    const float* __restrict__ h, const float* __restrict__ aw,
    const float* __restrict__ ab, const int* __restrict__ ei,
    float* __restrict__ ew)
{
    __shared__ float p[64], q[64], red[256];
    int t = threadIdx.x;
    if (t < 64) {
        float pp = 0.f, qq = 0.f;
        for (int c = 0; c < 256; c++) {
            float hv = h[t * 256 + c];
            pp += hv * aw[c];
            qq += hv * aw[256 + c];
        }
        p[t] = pp; q[t] = qq;
    }
    __syncthreads();
    int r = ei[t], c = ei[256 + t];
    float s = p[r] + q[c] + ab[0];
    s = s >= 0.f ? s : 0.01f * s;
    red[t] = s;
    __syncthreads();
    for (int st = 128; st > 0; st >>= 1) {
        if (t < st) red[t] = fmaxf(red[t], red[t + st]);
        __syncthreads();
    }
    float mx = red[0];
    __syncthreads();
    float e = expf(s - mx);
    red[t] = e;
    __syncthreads();
    for (int st = 128; st > 0; st >>= 1) {
        if (t < st) red[t] += red[t + st];
        __syncthreads();
    }
    ew[t] = e / red[0];
}

// ---------------- GCN aggregate + linear + residual (+ReLU) ----------------
__global__ __launch_bounds__(256) void gcn_agg(
    const float* __restrict__ h, const float* __restrict__ ew, const int* __restrict__ ei,
    const float* __restrict__ lw, const float* __restrict__ lb,
    float* __restrict__ ho)
{
    __shared__ float agg[256];
    __shared__ float ewl[256];
    __shared__ int rl[256], cl[256];
    int n = blockIdx.x;
    int t = threadIdx.x;
    ewl[t] = ew[t];
    rl[t] = ei[t];
    cl[t] = ei[256 + t];
    __syncthreads();
    float a = 0.f;
    for (int e = 0; e < 256; e++)
        if (rl[e] == n) a += ewl[e] * h[cl[e] * 256 + t];
    agg[t] = a;
    __syncthreads();
    float o = 0.f;
    for (int c2 = 0; c2 < 256; c2++)
        o += agg[c2] * lw[t * 256 + c2];
    o += lb[t] + h[n * 256 + t];
    o = o > 0.f ? o : 0.f;
    ho[n * 256 + t] = o;
}

// ---------------- final fc: [64,256] @ [50,256]^T + b -> f32 out ----------------
__global__ void fc_k(const float* __restrict__ h, const float* __restrict__ fw,
                     const float* __restrict__ fb, float* __restrict__ out)
{
    int n = blockIdx.x;
    int t = threadIdx.x;
    if (t < 50) {
        float o = 0.f;
        for (int c = 0; c < 256; c++)
            o += h[n * 256 + c] * fw[t * 256 + c];
        o += fb[t];
        out[n * 50 + t] = o;
    }
}

extern "C" void kernel_launch(void* const* d_in, const int* in_sizes, int n_in,
                              void* d_out, int out_size, void* d_ws, size_t ws_size,
                              hipStream_t stream)
{
    (void)in_sizes; (void)n_in; (void)out_size;

    const float* X    = (const float*)d_in[0];
    const float* c1w  = (const float*)d_in[1];
    const float* c1b  = (const float*)d_in[2];
    const float* b1g  = (const float*)d_in[3];
    const float* b1b  = (const float*)d_in[4];
    const float* b1m  = (const float*)d_in[5];
    const float* b1v  = (const float*)d_in[6];
    const float* c2w  = (const float*)d_in[7];
    const float* c2b  = (const float*)d_in[8];
    const float* b2g  = (const float*)d_in[9];
    const float* b2b  = (const float*)d_in[10];
    const float* b2m  = (const float*)d_in[11];
    const float* b2v  = (const float*)d_in[12];
    const float* c3w  = (const float*)d_in[13];
    const float* c3b  = (const float*)d_in[14];
    const float* b3g  = (const float*)d_in[15];
    const float* b3b  = (const float*)d_in[16];
    const float* b3m  = (const float*)d_in[17];
    const float* b3v  = (const float*)d_in[18];
    const float* g1lw = (const float*)d_in[19];
    const float* g1lb = (const float*)d_in[20];
    const float* g1aw = (const float*)d_in[21];
    const float* g1ab = (const float*)d_in[22];
    const float* g2lw = (const float*)d_in[23];
    const float* g2lb = (const float*)d_in[24];
    const float* g2aw = (const float*)d_in[25];
    const float* g2ab = (const float*)d_in[26];
    const float* fcw  = (const float*)d_in[27];
    const float* fcb  = (const float*)d_in[28];
    const int*   EI   = (const int*)d_in[29];

    // runtime chunk size: largest of {64,32,16} that fits (chb*NPOS must be /256)
    size_t fixedB = 3000000;
    int chb = 16;
    if (ws_size >= (size_t)64 * 5680128 + fixedB)      chb = 64;
    else if (ws_size >= (size_t)32 * 5680128 + fixedB) chb = 32;
    int nchunks = Bn / chb;
    int mch = chb * NPOS;                  // positions per chunk (div by 256)

    char* p = (char*)d_ws;
    auto carve = [&](size_t bytes) {
        char* r = p;
        p += (bytes + 255) & ~(size_t)255;
        return r;
    };
    __hip_bfloat16* h1c = (__hip_bfloat16*)carve((size_t)chb * HP * HP * C1c * 2);
    __hip_bfloat16* h2c = (__hip_bfloat16*)carve((size_t)chb * HP * HP * C2c * 2);
    __hip_bfloat16* wm2 = (__hip_bfloat16*)carve((size_t)9 * C1c * 256 * 2);
    __hip_bfloat16* wm3 = (__hip_bfloat16*)carve((size_t)9 * C2c * 256 * 2);
    float* sb2  = (float*)carve(512 * 4);
    float* sb3  = (float*)carve(512 * 4);
    float* pool = (float*)carve(64 * 256 * 4);
    float* h0   = (float*)carve(64 * 256 * 4);
    float* hg1  = (float*)carve(64 * 256 * 4);
    float* hg2  = (float*)carve(64 * 256 * 4);
    float* ew1  = (float*)carve(256 * 4);
    float* ew2  = (float*)carve(256 * 4);

    // prep (independent of conv outputs); halos stay zero across chunks/replays
    halo_zero<C1c><<<dim3(chb * 340), dim3(C1c), 0, stream>>>(h1c);
    halo_zero<C2c><<<dim3(chb * 340), dim3(C2c), 0, stream>>>(h2c);
    prep_w<C1c><<<dim3(9 * C1c), dim3(256), 0, stream>>>(c2w, wm2);
    prep_w<C2c><<<dim3(9 * C2c), dim3(256), 0, stream>>>(c3w, wm3);
    prep_sb<<<dim3(1), dim3(256), 0, stream>>>(c2b, b2g, b2b, b2m, b2v, sb2);
    prep_sb<<<dim3(1), dim3(256), 0, stream>>>(c3b, b3g, b3b, b3m, b3v, sb3);
    zero_f32<<<dim3(64), dim3(256), 0, stream>>>(pool);

    // conv chain, chunked over batch (chb images per chunk)
    for (int ch = 0; ch < nchunks; ch++) {
        const float* xch = X + (size_t)ch * chb * 3 * NPOS;
        conv1_k<<<dim3(chb * Hs), dim3(C1c), 0, stream>>>(
            xch, c1w, c1b, b1g, b1b, b1m, b1v, h1c);
        conv_igemm<C1c, false><<<dim3(mch / 256), dim3(512), 0, stream>>>(
            h1c, wm2, sb2, h2c, nullptr);
        conv_igemm<C2c, true ><<<dim3(mch / 256), dim3(512), 0, stream>>>(
            h2c, wm3, sb3, nullptr, pool + (size_t)ch * chb * 256);
    }
    pool_div<<<dim3(64), dim3(256), 0, stream>>>(pool, h0);

    // GCN layers + fc
    gcn_attn<<<dim3(1), dim3(256), 0, stream>>>(h0, g1aw, g1ab, EI, ew1);
    gcn_agg<<<dim3(64), dim3(256), 0, stream>>>(h0, ew1, EI, g1lw, g1lb, hg1);
    gcn_attn<<<dim3(1), dim3(256), 0, stream>>>(hg1, g2aw, g2ab, EI, ew2);
    gcn_agg<<<dim3(64), dim3(256), 0, stream>>>(hg1, ew2, EI, g2lw, g2lb, hg2);
    fc_k<<<dim3(64), dim3(64), 0, stream>>>(hg2, fcw, fcb, (float*)d_out);
}

// Round 13
// 896.403 us; speedup vs baseline: 1.3071x; 1.1236x over previous
//
#include <hip/hip_runtime.h>
#include <hip/hip_bf16.h>

typedef __attribute__((ext_vector_type(8))) short bf16x8;
typedef __attribute__((ext_vector_type(4))) float f32x4;

#define DEV __device__ __forceinline__

static constexpr int Bn   = 64;
static constexpr int Hs   = 84;
static constexpr int HP   = 86;
static constexpr int C1c  = 128;
static constexpr int C2c  = 256;
static constexpr int NPOS = Hs * Hs;       // 7056
static constexpr float EPSf = 1e-5f;

DEV __hip_bfloat16 f2b(float v) { return __float2bfloat16(v); }

// async global(16B/lane) -> LDS (wave-uniform base + lane*16)
DEV void gload16(const void* g, void* l) {
    __builtin_amdgcn_global_load_lds(
        (const __attribute__((address_space(1))) void*)g,
        (__attribute__((address_space(3))) void*)l, 16, 0, 0);
}

// ---------------- conv1: 3->128 direct conv + BN + ReLU, f32 in -> padded NHWC bf16 (one chunk) ----------------
__global__ __launch_bounds__(128) void conv1_k(
    const float* __restrict__ x,   // chunk base: [chb,3,84,84] f32
    const float* __restrict__ w,  const float* __restrict__ cb,
    const float* __restrict__ g,  const float* __restrict__ be,
    const float* __restrict__ mm, const float* __restrict__ vv,
    __hip_bfloat16* __restrict__ h1)        // [chb,86,86,128]
{
    __shared__ float xin[3][3][HP];
    int bi = blockIdx.x;
    int b = bi / Hs, y = bi % Hs;
    int t = threadIdx.x;

    for (int idx = t; idx < 3 * 3 * HP; idx += 128) {
        int ci = idx / (3 * HP);
        int r  = idx % (3 * HP);
        int dy = r / HP;
        int xx = r % HP;
        int iy = y + dy - 1;
        int ix = xx - 1;
        float v = 0.f;
        if (iy >= 0 && iy < Hs && ix >= 0 && ix < Hs)
            v = x[((size_t)(b * 3 + ci) * Hs + iy) * Hs + ix];
        xin[ci][dy][xx] = v;
    }
    int co = t;
    float wr[3][3][3];
    for (int ci = 0; ci < 3; ci++)
        for (int dy = 0; dy < 3; dy++)
            for (int dx = 0; dx < 3; dx++)
                wr[ci][dy][dx] = w[((co * 3 + ci) * 3 + dy) * 3 + dx];
    float scale = g[co] / sqrtf(vv[co] + EPSf);
    float bias  = (cb[co] - mm[co]) * scale + be[co];
    __syncthreads();

    for (int xp = 0; xp < Hs; xp++) {
        float acc = 0.f;
        #pragma unroll
        for (int ci = 0; ci < 3; ci++)
            #pragma unroll
            for (int dy = 0; dy < 3; dy++)
                #pragma unroll
                for (int dx = 0; dx < 3; dx++)
                    acc += xin[ci][dy][xp + dx] * wr[ci][dy][dx];
        float o = acc * scale + bias;
        o = o > 0.f ? o : 0.f;
        h1[((size_t)(b * HP + y + 1) * HP + (xp + 1)) * C1c + co] = f2b(o);
    }
}

// ---------------- zero the 1px halo of a padded NHWC chunk buffer ----------------
template <int C>
__global__ void halo_zero(__hip_bfloat16* __restrict__ h)
{
    int i = blockIdx.x;
    int b = i / 340, p = i % 340;
    int y, xx;
    if (p < 86)       { y = 0;  xx = p; }
    else if (p < 172) { y = 85; xx = p - 86; }
    else if (p < 256) { xx = 0; y = p - 172 + 1; }
    else              { xx = 85; y = p - 256 + 1; }
    h[((size_t)(b * HP + y) * HP + xx) * C + threadIdx.x] = f2b(0.f);
}

// ---------------- repack conv weights OIHW f32 -> [K/32][256][32] bf16 (k = tap*CIN + ci) ----------------
template <int CIN>
__global__ void prep_w(const float* __restrict__ w, __hip_bfloat16* __restrict__ wm)
{
    int e  = blockIdx.x * 256 + threadIdx.x;   // over (9*CIN) * 256
    int k  = e >> 8;
    int co = e & 255;
    int tap = k / CIN;
    int ci  = k % CIN;
    int ty = tap / 3, tx = tap % 3;
    wm[(size_t)(k >> 5) * 8192 + co * 32 + (k & 31)] =
        f2b(w[((size_t)(co * CIN + ci) * 3 + ty) * 3 + tx]);
}

// ---------------- per-channel BN fold: sb[0:256]=scale, sb[256:512]=bias ----------------
__global__ void prep_sb(const float* __restrict__ cb, const float* __restrict__ g,
                        const float* __restrict__ be, const float* __restrict__ mm,
                        const float* __restrict__ vv, float* __restrict__ sb)
{
    int co = threadIdx.x;
    float s = g[co] / sqrtf(vv[co] + EPSf);
    sb[co] = s;
    sb[256 + co] = (cb[co] - mm[co]) * s + be[co];
}

__global__ void zero_f32(float* __restrict__ p)
{
    p[blockIdx.x * 256 + threadIdx.x] = 0.f;
}

// ---------------- 256x256 2-phase/K-tile pipelined implicit-GEMM conv (3x3 SAME) ----------------
// BM=256, BN=256, BK=64; 512 thr / 8 waves (2M x 4N, wave 128x64).
// Double-buffered LDS (2 x 64 KB), counted vmcnt(4), ONE barrier per kh-phase
// (2 per K-tile; R12's extra 6 barriers + hard lgkmcnt(0) removed — hazard
// analysis: ISSUE always targets the other buffer; per-wave reads complete
// before the next K-tile barrier, so recycled-buffer writes can't race).
// Compiler emits fine-grained lgkmcnt(N) -> ds_read/MFMA overlap within wave.
// LDS planes per buffer: A_kh0 @0, A_kh1 @16K, B_kh0 @32K, B_kh1 @48K; 64B rows,
// involution swizzle (R11/R12: measured 0 conflicts). kb-outer/tap-inner K order.
// grid.x = chb*NPOS/256, block = 512.
template <int CIN, bool POOL>
__global__ __launch_bounds__(512, 2) void conv_igemm(
    const __hip_bfloat16* __restrict__ in, const __hip_bfloat16* __restrict__ wgt,
    const float* __restrict__ sb, __hip_bfloat16* __restrict__ out, float* __restrict__ pool)
{
    constexpr int KB = CIN / 32;
    constexpr int NK = 9 * KB / 2;             // K-tiles of 64 (18 or 36)
    constexpr unsigned BUFSZ = 65536u;         // 64 KB per buffer
    __shared__ __align__(16) char lds[2 * 65536];
    __shared__ float pl[512];

    int t = threadIdx.x;
    int l = t & 63, w = t >> 6;                // 8 waves
    int lidx = l & 15, lg = l >> 4;
    int wm = w >> 2, wn = w & 3;               // wave tile: rows wm*128.., cols wn*64..

    // bijective XCD-aware swizzle (m204)
    int nwg  = (int)gridDim.x;
    int orig = (int)blockIdx.x;
    int xcd = orig & 7, idx = orig >> 3;
    int q = nwg >> 3, r = nwg & 7;
    int bx = (xcd < r ? xcd * (q + 1) : r * (q + 1) + (xcd - r) * q) + idx;
    int m0 = bx * 256;

    // ---- staging lane sources: lane t stages rows (t>>2) and (t>>2)+128, PRE-SWIZZLED seg ----
    int seg  = (t & 3) ^ ((t >> 3) & 3);       // involution w/ row bits 1-2 (row = t>>2)
    int srow = t >> 2;                         // 0..127
    const __hip_bfloat16 *pA0, *pA1;
    {
        int gm = m0 + srow;
        int b0 = gm / NPOS; int r0 = gm - b0 * NPOS;
        int y0 = r0 / Hs;   int x0 = r0 - y0 * Hs;
        pA0 = in + ((size_t)(b0 * HP + y0) * HP + x0) * CIN + seg * 8;
        gm = m0 + 128 + srow;
        b0 = gm / NPOS; r0 = gm - b0 * NPOS;
        y0 = r0 / Hs;   x0 = r0 - y0 * Hs;
        pA1 = in + ((size_t)(b0 * HP + y0) * HP + x0) * CIN + seg * 8;
    }
    const __hip_bfloat16* pB0 = wgt + (size_t)srow * 32 + seg * 8;
    const __hip_bfloat16* pB1 = wgt + (size_t)(128 + srow) * 32 + seg * 8;

    // ---- frag ds_read byte offsets (within one 64 KB buffer, swizzled) ----
    int swz = (lidx >> 1) & 3;
    unsigned aRd[8][2], bRd[4][2];
    #pragma unroll
    for (int mf = 0; mf < 8; mf++)
        #pragma unroll
        for (int kh = 0; kh < 2; kh++)
            aRd[mf][kh] = (unsigned)(kh * 16384 + (wm * 128 + mf * 16 + lidx) * 64 + ((lg ^ swz) * 16));
    #pragma unroll
    for (int nf = 0; nf < 4; nf++)
        #pragma unroll
        for (int kh = 0; kh < 2; kh++)
            bRd[nf][kh] = (unsigned)(32768 + kh * 16384 + (wn * 64 + nf * 16 + lidx) * 64 + ((lg ^ swz) * 16));

    f32x4 acc[8][4];
    #pragma unroll
    for (int i = 0; i < 8; i++)
        #pragma unroll
        for (int j = 0; j < 4; j++)
            acc[i][j] = (f32x4){0.f, 0.f, 0.f, 0.f};
    if (POOL) pl[t] = 0.f;

    // sub-step s -> (kb = s/9 OUTER, tap = s%9 INNER): L2 locality (R6/R8 lesson)
    auto AOFF = [&](int s) -> size_t {
        int kb = s / 9, tap = s - kb * 9;
        int ty = tap / 3, tx = tap - ty * 3;
        return (size_t)(ty * HP + tx) * CIN + kb * 32;
    };
    auto BOFF = [&](int s) -> size_t {
        int kb = s / 9, tap = s - kb * 9;
        return (size_t)(tap * KB + kb) * 8192;
    };
    // stage kh-half of K-tile kt2 into buffer base bb (4 gloads = A 16KB + B 16KB)
    auto ISSUE = [&](int kt2, int kh, unsigned bb) {
        int s = 2 * kt2 + kh;
        size_t ao = AOFF(s), bo = BOFF(s);
        unsigned ap = bb + (unsigned)(kh * 16384) + (unsigned)(w * 1024);
        unsigned bp = bb + 32768u + (unsigned)(kh * 16384) + (unsigned)(w * 1024);
        gload16(pA0 + ao, lds + ap);
        gload16(pA1 + ao, lds + ap + 8192);
        gload16(pB0 + bo, lds + bp);
        gload16(pB1 + bo, lds + bp + 8192);
    };

    // prologue: stage both halves of K-tile 0 (8 loads in flight)
    ISSUE(0, 0, 0u);
    ISSUE(0, 1, 0u);

    for (int kt = 0; kt < NK; ++kt) {
        unsigned cb = (kt & 1) ? BUFSZ : 0u;
        unsigned nb = (kt & 1) ? 0u : BUFSZ;
        bool more = (kt + 1) < NK;

        #pragma unroll
        for (int kh = 0; kh < 2; ++kh) {
            // one vmcnt + one barrier per kh-phase
            if (kh == 0 || more) asm volatile("s_waitcnt vmcnt(4)" ::: "memory");
            else                 asm volatile("s_waitcnt vmcnt(0)" ::: "memory");
            __builtin_amdgcn_s_barrier();   // all waves' kh-half of tile kt landed
            asm volatile("" ::: "memory");

            bf16x8 av[8], bv[4];
            #pragma unroll
            for (int mf = 0; mf < 8; mf++)
                av[mf] = *(const bf16x8*)(lds + cb + aRd[mf][kh]);
            #pragma unroll
            for (int nf = 0; nf < 4; nf++)
                bv[nf] = *(const bf16x8*)(lds + cb + bRd[nf][kh]);
            if (more) ISSUE(kt + 1, kh, nb);
            // no hard lgkmcnt(0): compiler emits counted lgkmcnt(N), letting
            // leading MFMAs overlap trailing ds_reads within the wave
            __builtin_amdgcn_s_setprio(1);
            #pragma unroll
            for (int mf = 0; mf < 8; mf++)
                #pragma unroll
                for (int nf = 0; nf < 4; nf++)
                    acc[mf][nf] = __builtin_amdgcn_mfma_f32_16x16x32_bf16(
                        av[mf], bv[nf], acc[mf][nf], 0, 0, 0);
            __builtin_amdgcn_s_setprio(0);
        }
    }

    // ---- epilogue ----
    float sc[4], bi2[4];
    #pragma unroll
    for (int nf = 0; nf < 4; nf++) {
        int cn = wn * 64 + nf * 16 + lidx;
        sc[nf]  = sb[cn];
        bi2[nf] = sb[256 + cn];
    }

    if (!POOL) {
        #pragma unroll
        for (int mf = 0; mf < 8; mf++) {
            #pragma unroll
            for (int r2 = 0; r2 < 4; r2++) {
                int row = wm * 128 + mf * 16 + lg * 4 + r2;
                int gm2 = m0 + row;
                int b2  = gm2 / NPOS;
                int rm2 = gm2 - b2 * NPOS;
                int y2  = rm2 / Hs;
                int x2  = rm2 - y2 * Hs;
                size_t ob = ((size_t)(b2 * HP + y2 + 1) * HP + (x2 + 1)) * 256;
                #pragma unroll
                for (int nf = 0; nf < 4; nf++) {
                    float v = acc[mf][nf][r2] * sc[nf] + bi2[nf];
                    v = v > 0.f ? v : 0.f;
                    out[ob + wn * 64 + nf * 16 + lidx] = f2b(v);
                }
            }
        }
    } else {
        int bs_lo   = m0 / NPOS;
        int row_lim = (bs_lo + 1) * NPOS - m0;  // rows >= row_lim belong to image bs_lo+1
        __builtin_amdgcn_s_barrier();            // pl[] init visible
        #pragma unroll
        for (int nf = 0; nf < 4; nf++) {
            float s0 = 0.f, s1 = 0.f;
            #pragma unroll
            for (int mf = 0; mf < 8; mf++)
                #pragma unroll
                for (int r2 = 0; r2 < 4; r2++) {
                    int row = wm * 128 + mf * 16 + lg * 4 + r2;
                    float v = acc[mf][nf][r2] * sc[nf] + bi2[nf];
                    v = v > 0.f ? v : 0.f;
                    if (row < row_lim) s0 += v; else s1 += v;
                }
            int cl = wn * 64 + nf * 16 + lidx;   // [0,256)
            atomicAdd(&pl[cl], s0);
            if (row_lim < 256) atomicAdd(&pl[256 + cl], s1);
        }
        __syncthreads();
        if (t < 256)
            atomicAdd(&pool[bs_lo * 256 + t], pl[t]);
        else if (row_lim < 256)
            atomicAdd(&pool[(bs_lo + 1) * 256 + (t - 256)], pl[t]);
    }
}

// ---------------- pool finalize: mean ----------------
__global__ void pool_div(const float* __restrict__ pool, float* __restrict__ h0)
{
    int i = blockIdx.x * 256 + threadIdx.x;
    h0[i] = pool[i] * (1.0f / (float)NPOS);
}

// ---------------- GCN attention: ew = softmax(leaky(p[row]+q[col]+ab)) over 256 edges ----------------
__global__ __launch_bounds__(256) void gcn_attn(
    const float* __restrict__ h, const float* __restrict__ aw,
    const float* __restrict__ ab, const int* __restrict__ ei,
    float* __restrict__ ew)
{
    __shared__ float p[64], q[64], red[256];
    int t = threadIdx.x;
    if (t < 64) {
        float pp = 0.f, qq = 0.f;
        for (int c = 0; c < 256; c++) {
            float hv = h[t * 256 + c];
            pp += hv * aw[c];
            qq += hv * aw[256 + c];
        }
        p[t] = pp; q[t] = qq;
    }
    __syncthreads();
    int r = ei[t], c = ei[256 + t];
    float s = p[r] + q[c] + ab[0];
    s = s >= 0.f ? s : 0.01f * s;
    red[t] = s;
    __syncthreads();
    for (int st = 128; st > 0; st >>= 1) {
        if (t < st) red[t] = fmaxf(red[t], red[t + st]);
        __syncthreads();
    }
    float mx = red[0];
    __syncthreads();
    float e = expf(s - mx);
    red[t] = e;
    __syncthreads();
    for (int st = 128; st > 0; st >>= 1) {
        if (t < st) red[t] += red[t + st];
        __syncthreads();
    }
    ew[t] = e / red[0];
}

// ---------------- GCN aggregate + linear + residual (+ReLU) ----------------
__global__ __launch_bounds__(256) void gcn_agg(
    const float* __restrict__ h, const float* __restrict__ ew, const int* __restrict__ ei,
    const float* __restrict__ lw, const float* __restrict__ lb,
    float* __restrict__ ho)
{
    __shared__ float agg[256];
    __shared__ float ewl[256];
    __shared__ int rl[256], cl[256];
    int n = blockIdx.x;
    int t = threadIdx.x;
    ewl[t] = ew[t];
    rl[t] = ei[t];
    cl[t] = ei[256 + t];
    __syncthreads();
    float a = 0.f;
    for (int e = 0; e < 256; e++)
        if (rl[e] == n) a += ewl[e] * h[cl[e] * 256 + t];
    agg[t] = a;
    __syncthreads();
    float o = 0.f;
    for (int c2 = 0; c2 < 256; c2++)
        o += agg[c2] * lw[t * 256 + c2];
    o += lb[t] + h[n * 256 + t];
    o = o > 0.f ? o : 0.f;
    ho[n * 256 + t] = o;
}

// ---------------- final fc: [64,256] @ [50,256]^T + b -> f32 out ----------------
__global__ void fc_k(const float* __restrict__ h, const float* __restrict__ fw,
                     const float* __restrict__ fb, float* __restrict__ out)
{
    int n = blockIdx.x;
    int t = threadIdx.x;
    if (t < 50) {
        float o = 0.f;
        for (int c = 0; c < 256; c++)
            o += h[n * 256 + c] * fw[t * 256 + c];
        o += fb[t];
        out[n * 50 + t] = o;
    }
}

extern "C" void kernel_launch(void* const* d_in, const int* in_sizes, int n_in,
                              void* d_out, int out_size, void* d_ws, size_t ws_size,
                              hipStream_t stream)
{
    (void)in_sizes; (void)n_in; (void)out_size;

    const float* X    = (const float*)d_in[0];
    const float* c1w  = (const float*)d_in[1];
    const float* c1b  = (const float*)d_in[2];
    const float* b1g  = (const float*)d_in[3];
    const float* b1b  = (const float*)d_in[4];
    const float* b1m  = (const float*)d_in[5];
    const float* b1v  = (const float*)d_in[6];
    const float* c2w  = (const float*)d_in[7];
    const float* c2b  = (const float*)d_in[8];
    const float* b2g  = (const float*)d_in[9];
    const float* b2b  = (const float*)d_in[10];
    const float* b2m  = (const float*)d_in[11];
    const float* b2v  = (const float*)d_in[12];
    const float* c3w  = (const float*)d_in[13];
    const float* c3b  = (const float*)d_in[14];
    const float* b3g  = (const float*)d_in[15];
    const float* b3b  = (const float*)d_in[16];
    const float* b3m  = (const float*)d_in[17];
    const float* b3v  = (const float*)d_in[18];
    const float* g1lw = (const float*)d_in[19];
    const float* g1lb = (const float*)d_in[20];
    const float* g1aw = (const float*)d_in[21];
    const float* g1ab = (const float*)d_in[22];
    const float* g2lw = (const float*)d_in[23];
    const float* g2lb = (const float*)d_in[24];
    const float* g2aw = (const float*)d_in[25];
    const float* g2ab = (const float*)d_in[26];
    const float* fcw  = (const float*)d_in[27];
    const float* fcb  = (const float*)d_in[28];
    const int*   EI   = (const int*)d_in[29];

    // runtime chunk size: largest of {64,32,16} that fits (chb*NPOS must be /256)
    size_t fixedB = 3000000;
    int chb = 16;
    if (ws_size >= (size_t)64 * 5680128 + fixedB)      chb = 64;
    else if (ws_size >= (size_t)32 * 5680128 + fixedB) chb = 32;
    int nchunks = Bn / chb;
    int mch = chb * NPOS;                  // positions per chunk (div by 256)

    char* p = (char*)d_ws;
    auto carve = [&](size_t bytes) {
        char* r = p;
        p += (bytes + 255) & ~(size_t)255;
        return r;
    };
    __hip_bfloat16* h1c = (__hip_bfloat16*)carve((size_t)chb * HP * HP * C1c * 2);
    __hip_bfloat16* h2c = (__hip_bfloat16*)carve((size_t)chb * HP * HP * C2c * 2);
    __hip_bfloat16* wm2 = (__hip_bfloat16*)carve((size_t)9 * C1c * 256 * 2);
    __hip_bfloat16* wm3 = (__hip_bfloat16*)carve((size_t)9 * C2c * 256 * 2);
    float* sb2  = (float*)carve(512 * 4);
    float* sb3  = (float*)carve(512 * 4);
    float* pool = (float*)carve(64 * 256 * 4);
    float* h0   = (float*)carve(64 * 256 * 4);
    float* hg1  = (float*)carve(64 * 256 * 4);
    float* hg2  = (float*)carve(64 * 256 * 4);
    float* ew1  = (float*)carve(256 * 4);
    float* ew2  = (float*)carve(256 * 4);

    // prep (independent of conv outputs); halos stay zero across chunks/replays
    halo_zero<C1c><<<dim3(chb * 340), dim3(C1c), 0, stream>>>(h1c);
    halo_zero<C2c><<<dim3(chb * 340), dim3(C2c), 0, stream>>>(h2c);
    prep_w<C1c><<<dim3(9 * C1c), dim3(256), 0, stream>>>(c2w, wm2);
    prep_w<C2c><<<dim3(9 * C2c), dim3(256), 0, stream>>>(c3w, wm3);
    prep_sb<<<dim3(1), dim3(256), 0, stream>>>(c2b, b2g, b2b, b2m, b2v, sb2);
    prep_sb<<<dim3(1), dim3(256), 0, stream>>>(c3b, b3g, b3b, b3m, b3v, sb3);
    zero_f32<<<dim3(64), dim3(256), 0, stream>>>(pool);

    // conv chain, chunked over batch (chb images per chunk)
    for (int ch = 0; ch < nchunks; ch++) {
        const float* xch = X + (size_t)ch * chb * 3 * NPOS;
        conv1_k<<<dim3(chb * Hs), dim3(C1c), 0, stream>>>(
            xch, c1w, c1b, b1g, b1b, b1m, b1v, h1c);
        conv_igemm<C1c, false><<<dim3(mch / 256), dim3(512), 0, stream>>>(
            h1c, wm2, sb2, h2c, nullptr);
        conv_igemm<C2c, true ><<<dim3(mch / 256), dim3(512), 0, stream>>>(
            h2c, wm3, sb3, nullptr, pool + (size_t)ch * chb * 256);
    }
    pool_div<<<dim3(64), dim3(256), 0, stream>>>(pool, h0);

    // GCN layers + fc
    gcn_attn<<<dim3(1), dim3(256), 0, stream>>>(h0, g1aw, g1ab, EI, ew1);
    gcn_agg<<<dim3(64), dim3(256), 0, stream>>>(h0, ew1, EI, g1lw, g1lb, hg1);
    gcn_attn<<<dim3(1), dim3(256), 0, stream>>>(hg1, g2aw, g2ab, EI, ew2);
    gcn_agg<<<dim3(64), dim3(256), 0, stream>>>(hg1, ew2, EI, g2lw, g2lb, hg2);
    fc_k<<<dim3(64), dim3(64), 0, stream>>>(hg2, fcw, fcb, (float*)d_out);
}